// Round 3
// baseline (1280.224 us; speedup 1.0000x reference)
//
#include <hip/hip_runtime.h>
#include <cstdint>

#define S_LEN 3600
#define DMODEL 1536
#define LCTX 512
#define NH 12
#define HDIM 128
#define FFND 8960
#define SPAD_SELF 3648

typedef short v8s __attribute__((ext_vector_type(8)));
typedef float v4f __attribute__((ext_vector_type(4)));
typedef unsigned short u16b;
typedef unsigned int u32b;

__device__ __forceinline__ u16b f2b(float f){
  union { float f; u32b i; } x; x.f = f;
  u32b r = x.i + 0x7fffu + ((x.i >> 16) & 1u);
  return (u16b)(r >> 16);
}

__device__ __forceinline__ int swz4(int row){ return (row ^ (row >> 2)) & 3; }

// ---------------- small elementwise kernels ----------------
__global__ void add_vec(const float* __restrict__ a, const float* __restrict__ b,
                        float* __restrict__ o, int n){
  int i = blockIdx.x * 256 + threadIdx.x;
  if (i < n) o[i] = a[i] + b[i];
}

__global__ void f2b_kernel(const float* __restrict__ in, u16b* __restrict__ out, int n){
  int i = blockIdx.x * 256 + threadIdx.x;
  if (i < n) out[i] = f2b(in[i]);
}

// ---------------- fused transpose-convert of all weights ----------------
struct WJob { const float* W; u16b* WT; int K; int N; int t0; };
struct WJobs { WJob j[10]; };

__global__ __launch_bounds__(256) void wconv(WJobs jobs){
  __shared__ float tile[32][33];
  int b = blockIdx.x;
  int ji = 0;
  #pragma unroll
  for (int i = 0; i < 10; ++i) if (b >= jobs.j[i].t0) ji = i;
  WJob jb = jobs.j[ji];
  int rel = b - jb.t0;
  int ntn = jb.N / 32;
  int k0 = (rel / ntn) * 32, n0 = (rel % ntn) * 32;
  int tx = threadIdx.x & 31, ty = threadIdx.x >> 5;
  #pragma unroll
  for (int r = ty; r < 32; r += 8) tile[r][tx] = jb.W[(size_t)(k0 + r) * jb.N + n0 + tx];
  __syncthreads();
  #pragma unroll
  for (int r = ty; r < 32; r += 8) jb.WT[(size_t)(n0 + r) * jb.K + k0 + tx] = f2b(tile[tx][r]);
}

// ---------------- per-head V transpose: V[S][12*128] -> Vt[12][128][Spad] ----------------
__global__ __launch_bounds__(256) void vtrans(const u16b* __restrict__ V,
                                              u16b* __restrict__ Vt,
                                              int S, int Spad){
  __shared__ u16b t[32][136];
  int h = blockIdx.y, kb = blockIdx.x * 32, tid = threadIdx.x;
  int row = tid >> 3, ch = tid & 7;
  int key = kb + row;
  if (key < S){
    float4 a = *(const float4*)(V + (size_t)key * DMODEL + h * HDIM + ch * 16);
    float4 b = *(const float4*)(V + (size_t)key * DMODEL + h * HDIM + ch * 16 + 8);
    *(float4*)&t[row][ch * 16] = a;
    *(float4*)&t[row][ch * 16 + 8] = b;
  } else {
    float4 z = {0.f, 0.f, 0.f, 0.f};
    *(float4*)&t[row][ch * 16] = z;
    *(float4*)&t[row][ch * 16 + 8] = z;
  }
  __syncthreads();
  int hd = tid >> 1, kc = (tid & 1) * 16;
  u16b* dst = Vt + ((size_t)h * HDIM + hd) * Spad + kb + kc;
  #pragma unroll
  for (int e = 0; e < 16; e += 2){
    u32b pk = ((u32b)t[kc + e][hd]) | (((u32b)t[kc + e + 1][hd]) << 16);
    *(u32b*)(dst + e) = pk;
  }
}

// ---------------- LayerNorm (mod or affine) -> bf16 ----------------
__global__ __launch_bounds__(256) void ln_mod(const float* __restrict__ X,
                                              const float* __restrict__ gamma,
                                              const float* __restrict__ beta,
                                              float gadd, u16b* __restrict__ out){
  int row = blockIdx.x;
  const float* xr = X + (size_t)row * DMODEL;
  int tid = threadIdx.x;
  float v[6]; float s1 = 0.f, s2 = 0.f;
  #pragma unroll
  for (int j = 0; j < 6; ++j){ v[j] = xr[tid + j * 256]; s1 += v[j]; s2 += v[j] * v[j]; }
  #pragma unroll
  for (int o = 1; o < 64; o <<= 1){ s1 += __shfl_xor(s1, o); s2 += __shfl_xor(s2, o); }
  __shared__ float red[8];
  int wid = tid >> 6, lane = tid & 63;
  if (!lane){ red[wid * 2] = s1; red[wid * 2 + 1] = s2; }
  __syncthreads();
  s1 = red[0] + red[2] + red[4] + red[6];
  s2 = red[1] + red[3] + red[5] + red[7];
  float mu = s1 / DMODEL;
  float var = s2 / DMODEL - mu * mu;
  float rstd = rsqrtf(var + 1e-6f);
  #pragma unroll
  for (int j = 0; j < 6; ++j){
    int c = tid + j * 256;
    float g = gamma[c] + gadd;
    float b = beta[c];
    out[(size_t)row * DMODEL + c] = f2b((v[j] - mu) * rstd * g + b);
  }
}

// ---------------- RMSNorm (+optional RoPE) fp32 -> bf16 ----------------
__global__ __launch_bounds__(256) void rms_rope(const float* __restrict__ X,
                                                const float* __restrict__ w,
                                                const float* __restrict__ cosT,
                                                const float* __restrict__ sinT,
                                                u16b* __restrict__ out){
  int row = blockIdx.x;
  const float* xr = X + (size_t)row * DMODEL;
  int tid = threadIdx.x;
  float2 v[3]; float ss = 0.f;
  #pragma unroll
  for (int j = 0; j < 3; ++j){
    v[j] = *(const float2*)(xr + 2 * (tid + j * 256));
    ss += v[j].x * v[j].x + v[j].y * v[j].y;
  }
  #pragma unroll
  for (int o = 1; o < 64; o <<= 1) ss += __shfl_xor(ss, o);
  __shared__ float red[4];
  int wid = tid >> 6, lane = tid & 63;
  if (!lane) red[wid] = ss;
  __syncthreads();
  ss = red[0] + red[1] + red[2] + red[3];
  float rstd = rsqrtf(ss / DMODEL + 1e-6f);
  #pragma unroll
  for (int j = 0; j < 3; ++j){
    int p = tid + j * 256;
    float xe = v[j].x * rstd * w[2 * p];
    float xo = v[j].y * rstd * w[2 * p + 1];
    float oe, oo;
    if (cosT){
      int d = p & 63;
      float c = cosT[row * 64 + d], sn = sinT[row * 64 + d];
      oe = xe * c - xo * sn; oo = xe * sn + xo * c;
    } else { oe = xe; oo = xo; }
    u32b packed = ((u32b)f2b(oe)) | (((u32b)f2b(oo)) << 16);
    *(u32b*)(out + (size_t)row * DMODEL + 2 * p) = packed;
  }
}

// ---------------- bf16 MFMA GEMM: C = A[MxK] @ BT[NxK]^T + bias ----------------
// EPI: 0 = bf16 store, 1 = f32 store, 2 = f32 res + gate*(acc+bias), 3 = gelu->bf16
// EPI: 5 = split-K partial: out = acc to outF + z*M*N, k0 = z*kLen
template<int EPI>
__global__ __launch_bounds__(256, 2) void gemm_bt(
    const u16b* __restrict__ A, const u16b* __restrict__ BT,
    const float* __restrict__ bias, const float* __restrict__ res,
    const float* __restrict__ gate, float* __restrict__ outF,
    u16b* __restrict__ outB, int M, int N, int K, int kLen)
{
  __shared__ u16b Al[128 * 32];
  __shared__ u16b Bl[128 * 32];
  const int tid = threadIdx.x, lane = tid & 63, wid = tid >> 6;
  const int bm = blockIdx.x * 128, bn = blockIdx.y * 128;
  const int kbase = blockIdx.z * kLen;
  const int wm = (wid >> 1) * 64, wn = (wid & 1) * 64;
  v4f acc[4][4] = {};
  const int g0 = tid, g1 = tid + 256;
  const int r0 = g0 >> 2, c0 = g0 & 3, r1 = g1 >> 2, c1 = g1 & 3;
  const size_t a_off0 = (size_t)min(bm + r0, M - 1) * K + kbase + c0 * 8;
  const size_t a_off1 = (size_t)min(bm + r1, M - 1) * K + kbase + c1 * 8;
  const size_t b_off0 = (size_t)(bn + r0) * K + kbase + c0 * 8;
  const size_t b_off1 = (size_t)(bn + r1) * K + kbase + c1 * 8;
  char* Ab = (char*)Al; char* Bb = (char*)Bl;
  const int wA0 = r0 * 64 + ((c0 ^ swz4(r0)) * 16);
  const int wA1 = r1 * 64 + ((c1 ^ swz4(r1)) * 16);
  float4 ra0, ra1, rb0, rb1;
  auto ldg = [&](int k0){
    ra0 = *(const float4*)(A + a_off0 + k0);
    ra1 = *(const float4*)(A + a_off1 + k0);
    rb0 = *(const float4*)(BT + b_off0 + k0);
    rb1 = *(const float4*)(BT + b_off1 + k0);
  };
  auto stw = [&](){
    *(float4*)(Ab + wA0) = ra0; *(float4*)(Ab + wA1) = ra1;
    *(float4*)(Bb + wA0) = rb0; *(float4*)(Bb + wA1) = rb1;
  };
  const int nt = kLen / 32;
  ldg(0); stw(); __syncthreads();
  const int chk = lane >> 4, qr = lane & 15;
  for (int t = 0; t < nt; ++t){
    if (t + 1 < nt) ldg((t + 1) * 32);
    v8s af[4], bfr[4];
    #pragma unroll
    for (int f = 0; f < 4; ++f){
      int rowa = wm + f * 16 + qr;
      af[f] = *(const v8s*)(Ab + rowa * 64 + ((chk ^ swz4(rowa)) * 16));
      int rowb = wn + f * 16 + qr;
      bfr[f] = *(const v8s*)(Bb + rowb * 64 + ((chk ^ swz4(rowb)) * 16));
    }
    __builtin_amdgcn_s_setprio(1);
    #pragma unroll
    for (int i = 0; i < 4; ++i)
      #pragma unroll
      for (int j = 0; j < 4; ++j)
        acc[i][j] = __builtin_amdgcn_mfma_f32_16x16x32_bf16(af[i], bfr[j], acc[i][j], 0, 0, 0);
    __builtin_amdgcn_s_setprio(0);
    __syncthreads();
    if (t + 1 < nt){ stw(); __syncthreads(); }
  }
  const int rr = lane >> 4;
  #pragma unroll
  for (int i = 0; i < 4; ++i){
    #pragma unroll
    for (int j = 0; j < 4; ++j){
      int n = bn + wn + j * 16 + qr;
      float bv = (EPI != 5 && bias) ? bias[n] : 0.f;
      float gv = (EPI == 2 && gate) ? gate[n] : 1.f;
      #pragma unroll
      for (int r = 0; r < 4; ++r){
        int m = bm + wm + i * 16 + rr * 4 + r;
        if (m < M){
          float val = acc[i][j][r] + bv;
          size_t idx = (size_t)m * N + n;
          if (EPI == 0) outB[idx] = f2b(val);
          else if (EPI == 1) outF[idx] = val;
          else if (EPI == 2) outF[idx] = res[idx] + gv * val;
          else if (EPI == 5) outF[(size_t)blockIdx.z * M * N + idx] = val;
          else {
            float t3 = val * val * val;
            float th = tanhf(0.7978845608028654f * (val + 0.044715f * t3));
            outB[idx] = f2b(0.5f * val * (1.f + th));
          }
        }
      }
    }
  }
}

// ---------------- segmented GEMM (fused QKV / KV): N in 1536-wide segments ----------------
struct Seg { const float* bias; float* outF; u16b* outB; };
struct Segs { Seg s[3]; };

__global__ __launch_bounds__(256, 2) void gemm_seg(
    const u16b* __restrict__ A, const u16b* __restrict__ BT,
    Segs segs, int M, int N, int K)
{
  __shared__ u16b Al[128 * 32];
  __shared__ u16b Bl[128 * 32];
  const int tid = threadIdx.x, lane = tid & 63, wid = tid >> 6;
  const int bm = blockIdx.x * 128, bn = blockIdx.y * 128;
  const int wm = (wid >> 1) * 64, wn = (wid & 1) * 64;
  v4f acc[4][4] = {};
  const int g0 = tid, g1 = tid + 256;
  const int r0 = g0 >> 2, c0 = g0 & 3, r1 = g1 >> 2, c1 = g1 & 3;
  const size_t a_off0 = (size_t)min(bm + r0, M - 1) * K + c0 * 8;
  const size_t a_off1 = (size_t)min(bm + r1, M - 1) * K + c1 * 8;
  const size_t b_off0 = (size_t)(bn + r0) * K + c0 * 8;
  const size_t b_off1 = (size_t)(bn + r1) * K + c1 * 8;
  char* Ab = (char*)Al; char* Bb = (char*)Bl;
  const int wA0 = r0 * 64 + ((c0 ^ swz4(r0)) * 16);
  const int wA1 = r1 * 64 + ((c1 ^ swz4(r1)) * 16);
  float4 ra0, ra1, rb0, rb1;
  auto ldg = [&](int k0){
    ra0 = *(const float4*)(A + a_off0 + k0);
    ra1 = *(const float4*)(A + a_off1 + k0);
    rb0 = *(const float4*)(BT + b_off0 + k0);
    rb1 = *(const float4*)(BT + b_off1 + k0);
  };
  auto stw = [&](){
    *(float4*)(Ab + wA0) = ra0; *(float4*)(Ab + wA1) = ra1;
    *(float4*)(Bb + wA0) = rb0; *(float4*)(Bb + wA1) = rb1;
  };
  const int nt = K / 32;
  ldg(0); stw(); __syncthreads();
  const int chk = lane >> 4, qr = lane & 15;
  for (int t = 0; t < nt; ++t){
    if (t + 1 < nt) ldg((t + 1) * 32);
    v8s af[4], bfr[4];
    #pragma unroll
    for (int f = 0; f < 4; ++f){
      int rowa = wm + f * 16 + qr;
      af[f] = *(const v8s*)(Ab + rowa * 64 + ((chk ^ swz4(rowa)) * 16));
      int rowb = wn + f * 16 + qr;
      bfr[f] = *(const v8s*)(Bb + rowb * 64 + ((chk ^ swz4(rowb)) * 16));
    }
    __builtin_amdgcn_s_setprio(1);
    #pragma unroll
    for (int i = 0; i < 4; ++i)
      #pragma unroll
      for (int j = 0; j < 4; ++j)
        acc[i][j] = __builtin_amdgcn_mfma_f32_16x16x32_bf16(af[i], bfr[j], acc[i][j], 0, 0, 0);
    __builtin_amdgcn_s_setprio(0);
    __syncthreads();
    if (t + 1 < nt){ stw(); __syncthreads(); }
  }
  const int seg = bn / 1536;
  const Seg sg = segs.s[seg];
  const int rr = lane >> 4;
  #pragma unroll
  for (int i = 0; i < 4; ++i){
    #pragma unroll
    for (int j = 0; j < 4; ++j){
      int nloc = bn - seg * 1536 + wn + j * 16 + qr;
      float bv = sg.bias[nloc];
      #pragma unroll
      for (int r = 0; r < 4; ++r){
        int m = bm + wm + i * 16 + rr * 4 + r;
        if (m < M){
          float val = acc[i][j][r] + bv;
          size_t idx = (size_t)m * 1536 + nloc;
          if (sg.outB) sg.outB[idx] = f2b(val);
          else sg.outF[idx] = val;
        }
      }
    }
  }
}

// ---------------- FFN2 split-K reduce: out = res + gate*(p0+p1+bias) ----------------
__global__ __launch_bounds__(256) void ffn2_reduce(const float* __restrict__ part,
                                                   const float* __restrict__ res,
                                                   const float* __restrict__ bias,
                                                   const float* __restrict__ gate,
                                                   float* __restrict__ out, int total){
  int i4 = blockIdx.x * 256 + threadIdx.x;
  if (i4 * 4 >= total) return;
  int base = i4 * 4;
  int n = base % DMODEL;
  float4 p0 = *(const float4*)(part + base);
  float4 p1 = *(const float4*)(part + (size_t)total + base);
  float4 rs = *(const float4*)(res + base);
  float4 bv = *(const float4*)(bias + n);
  float4 gv = *(const float4*)(gate + n);
  float4 o;
  o.x = rs.x + gv.x * (p0.x + p1.x + bv.x);
  o.y = rs.y + gv.y * (p0.y + p1.y + bv.y);
  o.z = rs.z + gv.z * (p0.z + p1.z + bv.z);
  o.w = rs.w + gv.w * (p0.w + p1.w + bv.w);
  *(float4*)(out + base) = o;
}

// ---------------- flash attention: KVBLK=64, prefetch, defer-max ----------------
// V pre-transposed per head: Vt[h][hd 0..127][Spad keys]
__global__ __launch_bounds__(256, 2) void flash_attn(
    const u16b* __restrict__ Q, const u16b* __restrict__ Kp,
    const u16b* __restrict__ Vt, u16b* __restrict__ O,
    int Sq, int Sk, int Spad)
{
  __shared__ u16b Klds[64 * 128];   // [key][hd] rows 256B, 16 granules, swz ^(row&7)
  __shared__ u16b Vlds[128 * 64];   // [hd][key] rows 128B, 8 granules, swz ^(row&7)
  __shared__ u16b Plds[4 * 16 * 64];// per-wave [q 16][key 64] rows 128B swz ^(qq&7)
  const int tid = threadIdx.x, lane = tid & 63, wid = tid >> 6;
  const int h = blockIdx.y;
  const int q0 = blockIdx.x * 64 + wid * 16;
  const int qq = lane & 15, cc = lane >> 4;
  char* Kb = (char*)Klds; char* Vb = (char*)Vlds;
  char* Pb = (char*)Plds + wid * 2048;

  v8s qf[4];
  {
    int qrow = min(q0 + qq, Sq - 1);
    const u16b* qp = Q + (size_t)qrow * DMODEL + h * HDIM + cc * 8;
    #pragma unroll
    for (int ks = 0; ks < 4; ++ks) qf[ks] = *(const v8s*)(qp + ks * 32);
  }
  float mrun = -1e30f, lrun = 0.f;
  v4f oacc[8] = {};
  const float scale = 0.08838834764831845f; // 1/sqrt(128)
  const int nt = (Sk + 63) >> 6;

  float4 rk[4], rv[4];
  auto ldg = [&](int kb0){
    #pragma unroll
    for (int c = 0; c < 4; ++c){
      int g = tid + c * 256;
      int krow = g >> 4, kgc = g & 15;
      int key = min(kb0 + krow, Sk - 1);
      rk[c] = *(const float4*)(Kp + (size_t)key * DMODEL + h * HDIM + kgc * 8);
      int vr = g >> 3, vc = g & 7;
      rv[c] = *(const float4*)(Vt + ((size_t)h * HDIM + vr) * Spad + kb0 + vc * 8);
    }
  };
  auto stw = [&](){
    #pragma unroll
    for (int c = 0; c < 4; ++c){
      int g = tid + c * 256;
      int krow = g >> 4, kgc = g & 15;
      *(float4*)(Kb + krow * 256 + ((kgc ^ (krow & 7)) * 16)) = rk[c];
      int vr = g >> 3, vc = g & 7;
      *(float4*)(Vb + vr * 128 + ((vc ^ (vr & 7)) * 16)) = rv[c];
    }
  };
  ldg(0); stw(); __syncthreads();

  for (int t = 0; t < nt; ++t){
    int kb0 = t << 6;
    if (t + 1 < nt) ldg(kb0 + 64);
    // ---- QK^T: s[16], key = sub*16 + cc*4 + r ----
    float s[16];
    __builtin_amdgcn_s_setprio(1);
    #pragma unroll
    for (int sub = 0; sub < 4; ++sub){
      v4f sa = {0.f, 0.f, 0.f, 0.f};
      int row = sub * 16 + qq;
      #pragma unroll
      for (int ks = 0; ks < 4; ++ks){
        v8s kf = *(const v8s*)(Kb + row * 256 + (((ks * 4 + cc) ^ (row & 7)) * 16));
        sa = __builtin_amdgcn_mfma_f32_16x16x32_bf16(kf, qf[ks], sa, 0, 0, 0);
      }
      #pragma unroll
      for (int r = 0; r < 4; ++r) s[sub * 4 + r] = sa[r] * scale;
    }
    __builtin_amdgcn_s_setprio(0);
    if (kb0 + 64 > Sk){
      #pragma unroll
      for (int i = 0; i < 16; ++i){
        int key = kb0 + (i >> 2) * 16 + cc * 4 + (i & 3);
        if (key >= Sk) s[i] = -1e30f;
      }
    }
    // ---- online softmax with defer-max (T13) ----
    float pmax = s[0];
    #pragma unroll
    for (int i = 1; i < 16; ++i) pmax = fmaxf(pmax, s[i]);
    pmax = fmaxf(pmax, __shfl_xor(pmax, 16));
    pmax = fmaxf(pmax, __shfl_xor(pmax, 32));
    if (!__all(pmax <= mrun + 8.f)){
      float mnew = fmaxf(mrun, pmax);
      float alpha = __expf(mrun - mnew);
      mrun = mnew;
      float alr[4];
      #pragma unroll
      for (int r = 0; r < 4; ++r) alr[r] = __shfl(alpha, cc * 4 + r);
      #pragma unroll
      for (int f = 0; f < 8; ++f)
        #pragma unroll
        for (int r = 0; r < 4; ++r) oacc[f][r] *= alr[r];
      lrun *= alpha;
    }
    float p[16]; float csum = 0.f;
    #pragma unroll
    for (int i = 0; i < 16; ++i){ p[i] = __expf(s[i] - mrun); csum += p[i]; }
    csum += __shfl_xor(csum, 16);
    csum += __shfl_xor(csum, 32);
    lrun += csum;
    // ---- P -> per-wave LDS tile ----
    #pragma unroll
    for (int sub = 0; sub < 4; ++sub){
      u32b u01 = ((u32b)f2b(p[sub * 4 + 0])) | (((u32b)f2b(p[sub * 4 + 1])) << 16);
      u32b u23 = ((u32b)f2b(p[sub * 4 + 2])) | (((u32b)f2b(p[sub * 4 + 3])) << 16);
      int gI = sub * 2 + (cc >> 1);
      uint2 w2; w2.x = u01; w2.y = u23;
      *(uint2*)(Pb + qq * 128 + ((gI ^ (qq & 7)) * 16) + (cc & 1) * 8) = w2;
    }
    // ---- PV ----
    v8s pf0 = *(const v8s*)(Pb + qq * 128 + (((cc) ^ (qq & 7)) * 16));
    v8s pf1 = *(const v8s*)(Pb + qq * 128 + (((4 + cc) ^ (qq & 7)) * 16));
    __builtin_amdgcn_s_setprio(1);
    #pragma unroll
    for (int hdb = 0; hdb < 8; ++hdb){
      int row = hdb * 16 + qq;
      v8s vf0 = *(const v8s*)(Vb + row * 128 + (((cc) ^ (row & 7)) * 16));
      v8s vf1 = *(const v8s*)(Vb + row * 128 + (((4 + cc) ^ (row & 7)) * 16));
      oacc[hdb] = __builtin_amdgcn_mfma_f32_16x16x32_bf16(pf0, vf0, oacc[hdb], 0, 0, 0);
      oacc[hdb] = __builtin_amdgcn_mfma_f32_16x16x32_bf16(pf1, vf1, oacc[hdb], 0, 0, 0);
    }
    __builtin_amdgcn_s_setprio(0);
    __syncthreads();
    if (t + 1 < nt){ stw(); __syncthreads(); }
  }

  float linv = 1.f / lrun;
  float lr[4];
  #pragma unroll
  for (int r = 0; r < 4; ++r) lr[r] = __shfl(linv, cc * 4 + r);
  #pragma unroll
  for (int hdb = 0; hdb < 8; ++hdb)
    #pragma unroll
    for (int r = 0; r < 4; ++r){
      int qrow = q0 + cc * 4 + r;
      if (qrow < Sq)
        O[(size_t)qrow * DMODEL + h * HDIM + hdb * 16 + qq] = f2b(oacc[hdb][r] * lr[r]);
    }
}

// ---------------- host launch ----------------
extern "C" void kernel_launch(void* const* d_in, const int* in_sizes, int n_in,
                              void* d_out, int out_size, void* d_ws, size_t ws_size,
                              hipStream_t stream){
  (void)in_sizes; (void)n_in; (void)out_size; (void)ws_size;
  const float* x     = (const float*)d_in[0];
  const float* ctx   = (const float*)d_in[1];
  const float* t_mod = (const float*)d_in[2];
  const float* ropec = (const float*)d_in[3];
  const float* ropes = (const float*)d_in[4];
  const float* modu  = (const float*)d_in[5];
  const float* sa_qw = (const float*)d_in[6];  const float* sa_qb = (const float*)d_in[7];
  const float* sa_kw = (const float*)d_in[8];  const float* sa_kb = (const float*)d_in[9];
  const float* sa_vw = (const float*)d_in[10]; const float* sa_vb = (const float*)d_in[11];
  const float* sa_ow = (const float*)d_in[12]; const float* sa_ob = (const float*)d_in[13];
  const float* sa_nq = (const float*)d_in[14]; const float* sa_nk = (const float*)d_in[15];
  const float* ca_qw = (const float*)d_in[16]; const float* ca_qb = (const float*)d_in[17];
  const float* ca_kw = (const float*)d_in[18]; const float* ca_kb = (const float*)d_in[19];
  const float* ca_vw = (const float*)d_in[20]; const float* ca_vb = (const float*)d_in[21];
  const float* ca_ow = (const float*)d_in[22]; const float* ca_ob = (const float*)d_in[23];
  const float* ca_nq = (const float*)d_in[24]; const float* ca_nk = (const float*)d_in[25];
  const float* n3w   = (const float*)d_in[26]; const float* n3b   = (const float*)d_in[27];
  const float* fw1   = (const float*)d_in[28]; const float* fb1   = (const float*)d_in[29];
  const float* fw2   = (const float*)d_in[30]; const float* fb2   = (const float*)d_in[31];
  float* out = (float*)d_out;

  char* wsp = (char*)d_ws;
  size_t off = 0;
  auto alloc = [&](size_t b){ void* p = wsp + off; off += (b + 255) & ~(size_t)255; return p; };
  const size_t WW = (size_t)DMODEL * DMODEL * 2;
  // persistent (alive through FFN):
  float* modc = (float*)alloc(6 * DMODEL * 4);
  u16b* w1T   = (u16b*)alloc((size_t)FFND * DMODEL * 2);
  u16b* w2T   = (u16b*)alloc((size_t)DMODEL * FFND * 2);
  u16b* h_bf  = (u16b*)alloc((size_t)S_LEN * DMODEL * 2);
  float* pre0 = (float*)alloc((size_t)S_LEN * DMODEL * 4);
  // phase region (dead by FFN time) — fmid + split-K partials overlay it:
  size_t region0 = off;
  u16b* sa_qkvT = (u16b*)alloc(3 * WW);           // q | k | v contiguous
  u16b* sa_owT  = (u16b*)alloc(WW);
  u16b* ca_qwT  = (u16b*)alloc(WW);
  u16b* ca_kvT  = (u16b*)alloc(2 * WW);           // k | v contiguous
  u16b* ca_owT  = (u16b*)alloc(WW);
  float* x2    = (float*)alloc((size_t)S_LEN * DMODEL * 4);
  float* pre2  = (float*)alloc((size_t)LCTX * DMODEL * 4);
  u16b* qb     = (u16b*)alloc((size_t)S_LEN * DMODEL * 2);
  u16b* kb     = (u16b*)alloc((size_t)S_LEN * DMODEL * 2);
  u16b* vb     = (u16b*)alloc((size_t)S_LEN * DMODEL * 2);
  u16b* ab     = (u16b*)alloc((size_t)S_LEN * DMODEL * 2);
  u16b* ctxb   = (u16b*)alloc((size_t)LCTX * DMODEL * 2);
  u16b* k2b    = (u16b*)alloc((size_t)LCTX * DMODEL * 2);
  u16b* v2b    = (u16b*)alloc((size_t)LCTX * DMODEL * 2);
  u16b* vts    = (u16b*)alloc((size_t)NH * HDIM * SPAD_SELF * 2);
  u16b* vtc    = (u16b*)alloc((size_t)NH * HDIM * LCTX * 2);
  // FFN-phase overlay (region contents dead): fmid then partials
  u16b* fmid = (u16b*)(wsp + region0);
  float* fpart = (float*)(wsp + region0 + (size_t)S_LEN * FFND * 2);

  add_vec<<<36, 256, 0, stream>>>(modu, t_mod, modc, 6 * DMODEL);

  WJobs jobs; int t = 0;
  auto addjob = [&](int i, const float* w_, u16b* wt, int K, int N){
    jobs.j[i].W = w_; jobs.j[i].WT = wt; jobs.j[i].K = K; jobs.j[i].N = N; jobs.j[i].t0 = t;
    t += (K / 32) * (N / 32);
  };
  addjob(0, sa_qw, sa_qkvT,           DMODEL, DMODEL);
  addjob(1, sa_kw, sa_qkvT + WW,      DMODEL, DMODEL);  // WW elements? (WW bytes = WW/2 elems)
  addjob(2, sa_vw, sa_qkvT + WW,      DMODEL, DMODEL);
  // fix pointer arithmetic below (u16b* + elements): replaced after
  addjob(3, sa_ow, sa_owT, DMODEL, DMODEL);
  addjob(4, ca_qw, ca_qwT, DMODEL, DMODEL);
  addjob(5, ca_kw, ca_kvT, DMODEL, DMODEL);
  addjob(6, ca_vw, ca_kvT, DMODEL, DMODEL);
  addjob(7, ca_ow, ca_owT, DMODEL, DMODEL);
  addjob(8, fw1, w1T, DMODEL, FFND);
  addjob(9, fw2, w2T, FFND, DMODEL);
  // correct segment pointers (WW is bytes; element stride = DMODEL*DMODEL)
  jobs.j[1].WT = sa_qkvT + (size_t)DMODEL * DMODEL;
  jobs.j[2].WT = sa_qkvT + (size_t)2 * DMODEL * DMODEL;
  jobs.j[5].WT = ca_kvT;
  jobs.j[6].WT = ca_kvT + (size_t)DMODEL * DMODEL;
  wconv<<<t, 256, 0, stream>>>(jobs);

  f2b_kernel<<<(LCTX * DMODEL) / 256, 256, 0, stream>>>(ctx, ctxb, LCTX * DMODEL);

  // ---- self attention branch ----
  ln_mod<<<S_LEN, 256, 0, stream>>>(x, modc + DMODEL, modc, 1.f, h_bf);
  dim3 g12(29, 12), g42(4, 12);
  {
    Segs sg;
    sg.s[0] = { sa_qb, pre0, nullptr };
    sg.s[1] = { sa_kb, x2,   nullptr };
    sg.s[2] = { sa_vb, nullptr, vb   };
    gemm_seg<<<dim3(29, 36), 256, 0, stream>>>(h_bf, sa_qkvT, sg, S_LEN, 3 * DMODEL, DMODEL);
  }
  rms_rope<<<S_LEN, 256, 0, stream>>>(pre0, sa_nq, ropec, ropes, qb);
  rms_rope<<<S_LEN, 256, 0, stream>>>(x2, sa_nk, ropec, ropes, kb);
  vtrans<<<dim3(SPAD_SELF / 32, 12), 256, 0, stream>>>(vb, vts, S_LEN, SPAD_SELF);
  flash_attn<<<dim3(57, 12), 256, 0, stream>>>(qb, kb, vts, ab, S_LEN, S_LEN, SPAD_SELF);
  gemm_bt<2><<<g12, 256, 0, stream>>>(ab, sa_owT, sa_ob, x, modc + 2 * DMODEL, x2, nullptr, S_LEN, DMODEL, DMODEL, DMODEL);

  // ---- cross attention branch ----
  ln_mod<<<S_LEN, 256, 0, stream>>>(x2, n3w, n3b, 0.f, h_bf);
  gemm_bt<1><<<g12, 256, 0, stream>>>(h_bf, ca_qwT, ca_qb, nullptr, nullptr, pre0, nullptr, S_LEN, DMODEL, DMODEL, DMODEL);
  {
    Segs sg;
    sg.s[0] = { ca_kb, pre2, nullptr };
    sg.s[1] = { ca_vb, nullptr, v2b  };
    sg.s[2] = { ca_vb, nullptr, v2b  };
    gemm_seg<<<dim3(4, 24), 256, 0, stream>>>(ctxb, ca_kvT, sg, LCTX, 2 * DMODEL, DMODEL);
  }
  rms_rope<<<S_LEN, 256, 0, stream>>>(pre0, ca_nq, nullptr, nullptr, qb);
  rms_rope<<<LCTX, 256, 0, stream>>>(pre2, ca_nk, nullptr, nullptr, k2b);
  vtrans<<<dim3(16, 12), 256, 0, stream>>>(v2b, vtc, LCTX, LCTX);
  flash_attn<<<dim3(57, 12), 256, 0, stream>>>(qb, k2b, vtc, ab, S_LEN, LCTX, LCTX);
  gemm_bt<2><<<g12, 256, 0, stream>>>(ab, ca_owT, ca_ob, x2, nullptr, pre0, nullptr, S_LEN, DMODEL, DMODEL, DMODEL);

  // ---- FFN ----
  ln_mod<<<S_LEN, 256, 0, stream>>>(pre0, modc + 4 * DMODEL, modc + 3 * DMODEL, 1.f, h_bf);
  gemm_bt<3><<<dim3(29, 70), 256, 0, stream>>>(h_bf, w1T, fb1, nullptr, nullptr, nullptr, fmid, S_LEN, FFND, DMODEL, DMODEL);
  gemm_bt<5><<<dim3(29, 12, 2), 256, 0, stream>>>(fmid, w2T, nullptr, nullptr, nullptr, fpart, nullptr, S_LEN, DMODEL, FFND, FFND / 2);
  ffn2_reduce<<<(S_LEN * DMODEL / 4 + 255) / 256, 256, 0, stream>>>(fpart, pre0, fb2, modc + 5 * DMODEL, out, S_LEN * DMODEL);
}

// Round 4
// 1055.324 us; speedup vs baseline: 1.2131x; 1.2131x over previous
//
#include <hip/hip_runtime.h>
#include <cstdint>

#define S_LEN 3600
#define DMODEL 1536
#define LCTX 512
#define NH 12
#define HDIM 128
#define FFND 8960
#define SPAD_SELF 3648

typedef short v8s __attribute__((ext_vector_type(8)));
typedef float v4f __attribute__((ext_vector_type(4)));
typedef unsigned short u16b;
typedef unsigned int u32b;

#define AS1 __attribute__((address_space(1)))
#define AS3 __attribute__((address_space(3)))

__device__ __forceinline__ void gl_lds16(const void* g, void* l){
  __builtin_amdgcn_global_load_lds((AS1 const void*)g, (AS3 void*)l, 16, 0, 0);
}

__device__ __forceinline__ u16b f2b(float f){
  union { float f; u32b i; } x; x.f = f;
  u32b r = x.i + 0x7fffu + ((x.i >> 16) & 1u);
  return (u16b)(r >> 16);
}

__device__ __forceinline__ int swz4(int row){ return (row ^ (row >> 2)) & 3; }

// ---------------- small elementwise kernels ----------------
__global__ void add_vec(const float* __restrict__ a, const float* __restrict__ b,
                        float* __restrict__ o, int n){
  int i = blockIdx.x * 256 + threadIdx.x;
  if (i < n) o[i] = a[i] + b[i];
}

__global__ void f2b_kernel(const float* __restrict__ in, u16b* __restrict__ out, int n){
  int i = blockIdx.x * 256 + threadIdx.x;
  if (i < n) out[i] = f2b(in[i]);
}

// ---------------- fused transpose-convert of all weights ----------------
struct WJob { const float* W; u16b* WT; int K; int N; int t0; };
struct WJobs { WJob j[10]; };

__global__ __launch_bounds__(256) void wconv(WJobs jobs){
  __shared__ float tile[32][33];
  int b = blockIdx.x;
  int ji = 0;
  #pragma unroll
  for (int i = 0; i < 10; ++i) if (b >= jobs.j[i].t0) ji = i;
  WJob jb = jobs.j[ji];
  int rel = b - jb.t0;
  int ntn = jb.N / 32;
  int k0 = (rel / ntn) * 32, n0 = (rel % ntn) * 32;
  int tx = threadIdx.x & 31, ty = threadIdx.x >> 5;
  #pragma unroll
  for (int r = ty; r < 32; r += 8) tile[r][tx] = jb.W[(size_t)(k0 + r) * jb.N + n0 + tx];
  __syncthreads();
  #pragma unroll
  for (int r = ty; r < 32; r += 8) jb.WT[(size_t)(n0 + r) * jb.K + k0 + tx] = f2b(tile[tx][r]);
}

// ---------------- per-head V transpose: V[S][12*128] -> Vt[12][128][Spad] ----------------
__global__ __launch_bounds__(256) void vtrans(const u16b* __restrict__ V,
                                              u16b* __restrict__ Vt,
                                              int S, int Spad){
  __shared__ u16b t[32][136];
  int h = blockIdx.y, kb = blockIdx.x * 32, tid = threadIdx.x;
  int row = tid >> 3, ch = tid & 7;
  int key = kb + row;
  if (key < S){
    float4 a = *(const float4*)(V + (size_t)key * DMODEL + h * HDIM + ch * 16);
    float4 b = *(const float4*)(V + (size_t)key * DMODEL + h * HDIM + ch * 16 + 8);
    *(float4*)&t[row][ch * 16] = a;
    *(float4*)&t[row][ch * 16 + 8] = b;
  } else {
    float4 z = {0.f, 0.f, 0.f, 0.f};
    *(float4*)&t[row][ch * 16] = z;
    *(float4*)&t[row][ch * 16 + 8] = z;
  }
  __syncthreads();
  int hd = tid >> 1, kc = (tid & 1) * 16;
  u16b* dst = Vt + ((size_t)h * HDIM + hd) * Spad + kb + kc;
  #pragma unroll
  for (int e = 0; e < 16; e += 2){
    u32b pk = ((u32b)t[kc + e][hd]) | (((u32b)t[kc + e + 1][hd]) << 16);
    *(u32b*)(dst + e) = pk;
  }
}

// ---------------- LayerNorm (mod or affine) -> bf16 ----------------
__global__ __launch_bounds__(256) void ln_mod(const float* __restrict__ X,
                                              const float* __restrict__ gamma,
                                              const float* __restrict__ beta,
                                              float gadd, u16b* __restrict__ out){
  int row = blockIdx.x;
  const float* xr = X + (size_t)row * DMODEL;
  int tid = threadIdx.x;
  float v[6]; float s1 = 0.f, s2 = 0.f;
  #pragma unroll
  for (int j = 0; j < 6; ++j){ v[j] = xr[tid + j * 256]; s1 += v[j]; s2 += v[j] * v[j]; }
  #pragma unroll
  for (int o = 1; o < 64; o <<= 1){ s1 += __shfl_xor(s1, o); s2 += __shfl_xor(s2, o); }
  __shared__ float red[8];
  int wid = tid >> 6, lane = tid & 63;
  if (!lane){ red[wid * 2] = s1; red[wid * 2 + 1] = s2; }
  __syncthreads();
  s1 = red[0] + red[2] + red[4] + red[6];
  s2 = red[1] + red[3] + red[5] + red[7];
  float mu = s1 / DMODEL;
  float var = s2 / DMODEL - mu * mu;
  float rstd = rsqrtf(var + 1e-6f);
  #pragma unroll
  for (int j = 0; j < 6; ++j){
    int c = tid + j * 256;
    float g = gamma[c] + gadd;
    float b = beta[c];
    out[(size_t)row * DMODEL + c] = f2b((v[j] - mu) * rstd * g + b);
  }
}

// ---------------- RMSNorm (+optional RoPE) fp32 -> bf16 ----------------
__global__ __launch_bounds__(256) void rms_rope(const float* __restrict__ X,
                                                const float* __restrict__ w,
                                                const float* __restrict__ cosT,
                                                const float* __restrict__ sinT,
                                                u16b* __restrict__ out){
  int row = blockIdx.x;
  const float* xr = X + (size_t)row * DMODEL;
  int tid = threadIdx.x;
  float2 v[3]; float ss = 0.f;
  #pragma unroll
  for (int j = 0; j < 3; ++j){
    v[j] = *(const float2*)(xr + 2 * (tid + j * 256));
    ss += v[j].x * v[j].x + v[j].y * v[j].y;
  }
  #pragma unroll
  for (int o = 1; o < 64; o <<= 1) ss += __shfl_xor(ss, o);
  __shared__ float red[4];
  int wid = tid >> 6, lane = tid & 63;
  if (!lane) red[wid] = ss;
  __syncthreads();
  ss = red[0] + red[1] + red[2] + red[3];
  float rstd = rsqrtf(ss / DMODEL + 1e-6f);
  #pragma unroll
  for (int j = 0; j < 3; ++j){
    int p = tid + j * 256;
    float xe = v[j].x * rstd * w[2 * p];
    float xo = v[j].y * rstd * w[2 * p + 1];
    float oe, oo;
    if (cosT){
      int d = p & 63;
      float c = cosT[row * 64 + d], sn = sinT[row * 64 + d];
      oe = xe * c - xo * sn; oo = xe * sn + xo * c;
    } else { oe = xe; oo = xo; }
    u32b packed = ((u32b)f2b(oe)) | (((u32b)f2b(oo)) << 16);
    *(u32b*)(out + (size_t)row * DMODEL + 2 * p) = packed;
  }
}

// ---------------- bf16 MFMA GEMM (gload_lds dbuf, 1 barrier/K-step) ----------------
// EPI: 0 = bf16 store, 1 = f32 store, 2 = f32 res + gate*(acc+bias), 3 = gelu->bf16
// EPI: 5 = split-K partial to outF + z*M*N
template<int EPI>
__global__ __launch_bounds__(256, 2) void gemm_bt(
    const u16b* __restrict__ A, const u16b* __restrict__ BT,
    const float* __restrict__ bias, const float* __restrict__ res,
    const float* __restrict__ gate, float* __restrict__ outF,
    u16b* __restrict__ outB, int M, int N, int K, int kLen)
{
  __shared__ char Asm[2][8192];
  __shared__ char Bsm[2][8192];
  const int tid = threadIdx.x, lane = tid & 63, wid = tid >> 6;
  const int bm = blockIdx.x * 128, bn = blockIdx.y * 128;
  const int kbase = blockIdx.z * kLen;
  const int wm = (wid >> 1) * 64, wn = (wid & 1) * 64;
  v4f acc[4][4] = {};

  auto stage = [&](int buf, int k0){
    #pragma unroll
    for (int c = 0; c < 2; ++c){
      int seg = wid * 2 + c;
      int l = seg * 64 + lane;
      int row = l >> 2, cs = l & 3;
      int col = cs ^ swz4(row);
      gl_lds16(A + (size_t)min(bm + row, M - 1) * K + kbase + k0 + col * 8,
               Asm[buf] + seg * 1024);
      gl_lds16(BT + (size_t)(bn + row) * K + kbase + k0 + col * 8,
               Bsm[buf] + seg * 1024);
    }
  };

  const int nt = kLen / 32;
  int cur = 0;
  stage(0, 0);
  __syncthreads();
  const int chk = lane >> 4, qr = lane & 15;
  for (int t = 0; t < nt; ++t){
    if (t + 1 < nt) stage(cur ^ 1, (t + 1) * 32);
    char* Ab = Asm[cur]; char* Bb = Bsm[cur];
    v8s af[4], bfr[4];
    #pragma unroll
    for (int f = 0; f < 4; ++f){
      int rowa = wm + f * 16 + qr;
      af[f] = *(const v8s*)(Ab + rowa * 64 + ((chk ^ swz4(rowa)) * 16));
      int rowb = wn + f * 16 + qr;
      bfr[f] = *(const v8s*)(Bb + rowb * 64 + ((chk ^ swz4(rowb)) * 16));
    }
    __builtin_amdgcn_s_setprio(1);
    #pragma unroll
    for (int i = 0; i < 4; ++i)
      #pragma unroll
      for (int j = 0; j < 4; ++j)
        acc[i][j] = __builtin_amdgcn_mfma_f32_16x16x32_bf16(af[i], bfr[j], acc[i][j], 0, 0, 0);
    __builtin_amdgcn_s_setprio(0);
    __syncthreads();
    cur ^= 1;
  }
  const int rr = lane >> 4;
  #pragma unroll
  for (int i = 0; i < 4; ++i){
    #pragma unroll
    for (int j = 0; j < 4; ++j){
      int n = bn + wn + j * 16 + qr;
      float bv = (EPI != 5 && bias) ? bias[n] : 0.f;
      float gv = (EPI == 2 && gate) ? gate[n] : 1.f;
      #pragma unroll
      for (int r = 0; r < 4; ++r){
        int m = bm + wm + i * 16 + rr * 4 + r;
        if (m < M){
          float val = acc[i][j][r] + bv;
          size_t idx = (size_t)m * N + n;
          if (EPI == 0) outB[idx] = f2b(val);
          else if (EPI == 1) outF[idx] = val;
          else if (EPI == 2) outF[idx] = res[idx] + gv * val;
          else if (EPI == 5) outF[(size_t)blockIdx.z * M * N + idx] = val;
          else {
            float t3 = val * val * val;
            float th = tanhf(0.7978845608028654f * (val + 0.044715f * t3));
            outB[idx] = f2b(0.5f * val * (1.f + th));
          }
        }
      }
    }
  }
}

// ---------------- segmented GEMM (fused QKV / KV) ----------------
struct Seg { const float* bias; float* outF; u16b* outB; };
struct Segs { Seg s[3]; };

__global__ __launch_bounds__(256, 2) void gemm_seg(
    const u16b* __restrict__ A, const u16b* __restrict__ BT,
    Segs segs, int M, int N, int K)
{
  __shared__ char Asm[2][8192];
  __shared__ char Bsm[2][8192];
  const int tid = threadIdx.x, lane = tid & 63, wid = tid >> 6;
  const int bm = blockIdx.x * 128, bn = blockIdx.y * 128;
  const int wm = (wid >> 1) * 64, wn = (wid & 1) * 64;
  v4f acc[4][4] = {};

  auto stage = [&](int buf, int k0){
    #pragma unroll
    for (int c = 0; c < 2; ++c){
      int seg = wid * 2 + c;
      int l = seg * 64 + lane;
      int row = l >> 2, cs = l & 3;
      int col = cs ^ swz4(row);
      gl_lds16(A + (size_t)min(bm + row, M - 1) * K + k0 + col * 8,
               Asm[buf] + seg * 1024);
      gl_lds16(BT + (size_t)(bn + row) * K + k0 + col * 8,
               Bsm[buf] + seg * 1024);
    }
  };

  const int nt = K / 32;
  int cur = 0;
  stage(0, 0);
  __syncthreads();
  const int chk = lane >> 4, qr = lane & 15;
  for (int t = 0; t < nt; ++t){
    if (t + 1 < nt) stage(cur ^ 1, (t + 1) * 32);
    char* Ab = Asm[cur]; char* Bb = Bsm[cur];
    v8s af[4], bfr[4];
    #pragma unroll
    for (int f = 0; f < 4; ++f){
      int rowa = wm + f * 16 + qr;
      af[f] = *(const v8s*)(Ab + rowa * 64 + ((chk ^ swz4(rowa)) * 16));
      int rowb = wn + f * 16 + qr;
      bfr[f] = *(const v8s*)(Bb + rowb * 64 + ((chk ^ swz4(rowb)) * 16));
    }
    __builtin_amdgcn_s_setprio(1);
    #pragma unroll
    for (int i = 0; i < 4; ++i)
      #pragma unroll
      for (int j = 0; j < 4; ++j)
        acc[i][j] = __builtin_amdgcn_mfma_f32_16x16x32_bf16(af[i], bfr[j], acc[i][j], 0, 0, 0);
    __builtin_amdgcn_s_setprio(0);
    __syncthreads();
    cur ^= 1;
  }
  const int seg = bn / 1536;
  const Seg sg = segs.s[seg];
  const int rr = lane >> 4;
  #pragma unroll
  for (int i = 0; i < 4; ++i){
    #pragma unroll
    for (int j = 0; j < 4; ++j){
      int nloc = bn - seg * 1536 + wn + j * 16 + qr;
      float bv = sg.bias[nloc];
      #pragma unroll
      for (int r = 0; r < 4; ++r){
        int m = bm + wm + i * 16 + rr * 4 + r;
        if (m < M){
          float val = acc[i][j][r] + bv;
          size_t idx = (size_t)m * 1536 + nloc;
          if (sg.outB) sg.outB[idx] = f2b(val);
          else sg.outF[idx] = val;
        }
      }
    }
  }
}

// ---------------- FFN2 split-K reduce ----------------
__global__ __launch_bounds__(256) void ffn2_reduce(const float* __restrict__ part,
                                                   const float* __restrict__ res,
                                                   const float* __restrict__ bias,
                                                   const float* __restrict__ gate,
                                                   float* __restrict__ out, int total){
  int i4 = blockIdx.x * 256 + threadIdx.x;
  if (i4 * 4 >= total) return;
  int base = i4 * 4;
  int n = base % DMODEL;
  float4 p0 = *(const float4*)(part + base);
  float4 p1 = *(const float4*)(part + (size_t)total + base);
  float4 rs = *(const float4*)(res + base);
  float4 bv = *(const float4*)(bias + n);
  float4 gv = *(const float4*)(gate + n);
  float4 o;
  o.x = rs.x + gv.x * (p0.x + p1.x + bv.x);
  o.y = rs.y + gv.y * (p0.y + p1.y + bv.y);
  o.z = rs.z + gv.z * (p0.z + p1.z + bv.z);
  o.w = rs.w + gv.w * (p0.w + p1.w + bv.w);
  *(float4*)(out + base) = o;
}

// ---------------- flash attention: KVBLK=64, gload_lds dbuf, 1 barrier/tile ----------------
// V pre-transposed per head: Vt[h][hd 0..127][Spad keys]
__global__ __launch_bounds__(256, 2) void flash_attn(
    const u16b* __restrict__ Q, const u16b* __restrict__ Kp,
    const u16b* __restrict__ Vt, u16b* __restrict__ O,
    int Sq, int Sk, int Spad)
{
  __shared__ char KV[2][32768];   // per buf: K 16KB [key 64][hd granules swz], V 16KB [hd 128][key granules swz]
  __shared__ char Pall[8192];     // per wave 2KB: [q 16][key 64] swz
  const int tid = threadIdx.x, lane = tid & 63, wid = tid >> 6;
  const int h = blockIdx.y;
  const int q0 = blockIdx.x * 64 + wid * 16;
  const int qq = lane & 15, cc = lane >> 4;
  char* Pb = Pall + wid * 2048;

  v8s qf[4];
  {
    int qrow = min(q0 + qq, Sq - 1);
    const u16b* qp = Q + (size_t)qrow * DMODEL + h * HDIM + cc * 8;
    #pragma unroll
    for (int ks = 0; ks < 4; ++ks) qf[ks] = *(const v8s*)(qp + ks * 32);
  }

  auto stage = [&](int buf, int kb0){
    char* base = KV[buf];
    #pragma unroll
    for (int c = 0; c < 4; ++c){
      int seg = wid * 4 + c;
      int g = seg * 64 + lane;
      int krow = g >> 4, kcol = (g & 15) ^ (krow & 7);
      gl_lds16(Kp + (size_t)min(kb0 + krow, Sk - 1) * DMODEL + h * HDIM + kcol * 8,
               base + seg * 1024);
      int vrow = g >> 3, vcol = (g & 7) ^ (vrow & 7);
      gl_lds16(Vt + ((size_t)h * HDIM + vrow) * Spad + kb0 + vcol * 8,
               base + 16384 + seg * 1024);
    }
  };

  float mrun = -1e30f, lrun = 0.f;
  v4f oacc[8] = {};
  const float scale = 0.08838834764831845f; // 1/sqrt(128)
  const int nt = (Sk + 63) >> 6;
  int cur = 0;
  stage(0, 0);
  __syncthreads();

  for (int t = 0; t < nt; ++t){
    if (t + 1 < nt) stage(cur ^ 1, (t + 1) << 6);
    char* Kb = KV[cur]; char* Vb = KV[cur] + 16384;
    int kb0 = t << 6;
    // ---- QK^T: sc[sub][r], key = sub*16 + cc*4 + r ----
    v4f sc[4];
    __builtin_amdgcn_s_setprio(1);
    #pragma unroll
    for (int sub = 0; sub < 4; ++sub){
      v4f sa = {0.f, 0.f, 0.f, 0.f};
      int row = sub * 16 + qq;
      #pragma unroll
      for (int ks = 0; ks < 4; ++ks){
        v8s kf = *(const v8s*)(Kb + row * 256 + (((ks * 4 + cc) ^ (row & 7)) * 16));
        sa = __builtin_amdgcn_mfma_f32_16x16x32_bf16(kf, qf[ks], sa, 0, 0, 0);
      }
      sc[sub] = sa;
    }
    __builtin_amdgcn_s_setprio(0);
    // scale (+ tail mask)
    #pragma unroll
    for (int sub = 0; sub < 4; ++sub)
      #pragma unroll
      for (int r = 0; r < 4; ++r) sc[sub][r] *= scale;
    if (kb0 + 64 > Sk){
      #pragma unroll
      for (int sub = 0; sub < 4; ++sub)
        #pragma unroll
        for (int r = 0; r < 4; ++r)
          if (kb0 + sub * 16 + cc * 4 + r >= Sk) sc[sub][r] = -1e30f;
    }
    // ---- online softmax, defer-max (T13) ----
    float pmax = sc[0][0];
    #pragma unroll
    for (int sub = 0; sub < 4; ++sub)
      #pragma unroll
      for (int r = 0; r < 4; ++r) pmax = fmaxf(pmax, sc[sub][r]);
    pmax = fmaxf(pmax, __shfl_xor(pmax, 16));
    pmax = fmaxf(pmax, __shfl_xor(pmax, 32));
    if (!__all(pmax <= mrun + 8.f)){
      float mnew = fmaxf(mrun, pmax);
      float alpha = __expf(mrun - mnew);
      mrun = mnew;
      float alr[4];
      #pragma unroll
      for (int r = 0; r < 4; ++r) alr[r] = __shfl(alpha, cc * 4 + r);
      #pragma unroll
      for (int f = 0; f < 8; ++f)
        #pragma unroll
        for (int r = 0; r < 4; ++r) oacc[f][r] *= alr[r];
      lrun *= alpha;
    }
    float csum = 0.f;
    #pragma unroll
    for (int sub = 0; sub < 4; ++sub)
      #pragma unroll
      for (int r = 0; r < 4; ++r){
        float p = __expf(sc[sub][r] - mrun);
        sc[sub][r] = p; csum += p;
      }
    csum += __shfl_xor(csum, 16);
    csum += __shfl_xor(csum, 32);
    lrun += csum;
    // ---- P -> per-wave LDS tile ----
    #pragma unroll
    for (int sub = 0; sub < 4; ++sub){
      u32b u01 = ((u32b)f2b(sc[sub][0])) | (((u32b)f2b(sc[sub][1])) << 16);
      u32b u23 = ((u32b)f2b(sc[sub][2])) | (((u32b)f2b(sc[sub][3])) << 16);
      int gI = sub * 2 + (cc >> 1);
      uint2 w2; w2.x = u01; w2.y = u23;
      *(uint2*)(Pb + qq * 128 + ((gI ^ (qq & 7)) * 16) + (cc & 1) * 8) = w2;
    }
    // ---- PV ----
    v8s pf0 = *(const v8s*)(Pb + qq * 128 + (((cc) ^ (qq & 7)) * 16));
    v8s pf1 = *(const v8s*)(Pb + qq * 128 + (((4 + cc) ^ (qq & 7)) * 16));
    __builtin_amdgcn_s_setprio(1);
    #pragma unroll
    for (int hdb = 0; hdb < 8; ++hdb){
      int row = hdb * 16 + qq;
      v8s vf0 = *(const v8s*)(Vb + row * 128 + (((cc) ^ (row & 7)) * 16));
      v8s vf1 = *(const v8s*)(Vb + row * 128 + (((4 + cc) ^ (row & 7)) * 16));
      oacc[hdb] = __builtin_amdgcn_mfma_f32_16x16x32_bf16(pf0, vf0, oacc[hdb], 0, 0, 0);
      oacc[hdb] = __builtin_amdgcn_mfma_f32_16x16x32_bf16(pf1, vf1, oacc[hdb], 0, 0, 0);
    }
    __builtin_amdgcn_s_setprio(0);
    __syncthreads();   // drains vmcnt (stage t+1) + closes tile
    cur ^= 1;
  }

  float linv = 1.f / lrun;
  float lr[4];
  #pragma unroll
  for (int r = 0; r < 4; ++r) lr[r] = __shfl(linv, cc * 4 + r);
  #pragma unroll
  for (int hdb = 0; hdb < 8; ++hdb)
    #pragma unroll
    for (int r = 0; r < 4; ++r){
      int qrow = q0 + cc * 4 + r;
      if (qrow < Sq)
        O[(size_t)qrow * DMODEL + h * HDIM + hdb * 16 + qq] = f2b(oacc[hdb][r] * lr[r]);
    }
}

// ---------------- host launch ----------------
extern "C" void kernel_launch(void* const* d_in, const int* in_sizes, int n_in,
                              void* d_out, int out_size, void* d_ws, size_t ws_size,
                              hipStream_t stream){
  (void)in_sizes; (void)n_in; (void)out_size; (void)ws_size;
  const float* x     = (const float*)d_in[0];
  const float* ctx   = (const float*)d_in[1];
  const float* t_mod = (const float*)d_in[2];
  const float* ropec = (const float*)d_in[3];
  const float* ropes = (const float*)d_in[4];
  const float* modu  = (const float*)d_in[5];
  const float* sa_qw = (const float*)d_in[6];  const float* sa_qb = (const float*)d_in[7];
  const float* sa_kw = (const float*)d_in[8];  const float* sa_kb = (const float*)d_in[9];
  const float* sa_vw = (const float*)d_in[10]; const float* sa_vb = (const float*)d_in[11];
  const float* sa_ow = (const float*)d_in[12]; const float* sa_ob = (const float*)d_in[13];
  const float* sa_nq = (const float*)d_in[14]; const float* sa_nk = (const float*)d_in[15];
  const float* ca_qw = (const float*)d_in[16]; const float* ca_qb = (const float*)d_in[17];
  const float* ca_kw = (const float*)d_in[18]; const float* ca_kb = (const float*)d_in[19];
  const float* ca_vw = (const float*)d_in[20]; const float* ca_vb = (const float*)d_in[21];
  const float* ca_ow = (const float*)d_in[22]; const float* ca_ob = (const float*)d_in[23];
  const float* ca_nq = (const float*)d_in[24]; const float* ca_nk = (const float*)d_in[25];
  const float* n3w   = (const float*)d_in[26]; const float* n3b   = (const float*)d_in[27];
  const float* fw1   = (const float*)d_in[28]; const float* fb1   = (const float*)d_in[29];
  const float* fw2   = (const float*)d_in[30]; const float* fb2   = (const float*)d_in[31];
  float* out = (float*)d_out;

  char* wsp = (char*)d_ws;
  size_t off = 0;
  auto alloc = [&](size_t b){ void* p = wsp + off; off += (b + 255) & ~(size_t)255; return p; };
  const size_t WW = (size_t)DMODEL * DMODEL * 2;
  // persistent (alive through FFN):
  float* modc = (float*)alloc(6 * DMODEL * 4);
  u16b* w1T   = (u16b*)alloc((size_t)FFND * DMODEL * 2);
  u16b* w2T   = (u16b*)alloc((size_t)DMODEL * FFND * 2);
  u16b* h_bf  = (u16b*)alloc((size_t)S_LEN * DMODEL * 2);
  float* pre0 = (float*)alloc((size_t)S_LEN * DMODEL * 4);
  // phase region (dead by FFN time) — fmid + split-K partials overlay it:
  size_t region0 = off;
  u16b* sa_qkvT = (u16b*)alloc(3 * WW);           // q | k | v contiguous
  u16b* sa_owT  = (u16b*)alloc(WW);
  u16b* ca_qwT  = (u16b*)alloc(WW);
  u16b* ca_kvT  = (u16b*)alloc(2 * WW);           // k | v contiguous
  u16b* ca_owT  = (u16b*)alloc(WW);
  float* x2    = (float*)alloc((size_t)S_LEN * DMODEL * 4);
  float* pre2  = (float*)alloc((size_t)LCTX * DMODEL * 4);
  u16b* qb     = (u16b*)alloc((size_t)S_LEN * DMODEL * 2);
  u16b* kb     = (u16b*)alloc((size_t)S_LEN * DMODEL * 2);
  u16b* vb     = (u16b*)alloc((size_t)S_LEN * DMODEL * 2);
  u16b* ab     = (u16b*)alloc((size_t)S_LEN * DMODEL * 2);
  u16b* ctxb   = (u16b*)alloc((size_t)LCTX * DMODEL * 2);
  u16b* k2b    = (u16b*)alloc((size_t)LCTX * DMODEL * 2);
  u16b* v2b    = (u16b*)alloc((size_t)LCTX * DMODEL * 2);
  u16b* vts    = (u16b*)alloc((size_t)NH * HDIM * SPAD_SELF * 2);
  u16b* vtc    = (u16b*)alloc((size_t)NH * HDIM * LCTX * 2);
  // FFN-phase overlay (region contents dead): fmid then partials
  u16b* fmid = (u16b*)(wsp + region0);
  float* fpart = (float*)(wsp + region0 + (size_t)S_LEN * FFND * 2);

  add_vec<<<36, 256, 0, stream>>>(modu, t_mod, modc, 6 * DMODEL);

  WJobs jobs; int t = 0;
  auto addjob = [&](int i, const float* w_, u16b* wt, int K, int N){
    jobs.j[i].W = w_; jobs.j[i].WT = wt; jobs.j[i].K = K; jobs.j[i].N = N; jobs.j[i].t0 = t;
    t += (K / 32) * (N / 32);
  };
  addjob(0, sa_qw, sa_qkvT, DMODEL, DMODEL);
  addjob(1, sa_kw, sa_qkvT + (size_t)DMODEL * DMODEL, DMODEL, DMODEL);
  addjob(2, sa_vw, sa_qkvT + (size_t)2 * DMODEL * DMODEL, DMODEL, DMODEL);
  addjob(3, sa_ow, sa_owT, DMODEL, DMODEL);
  addjob(4, ca_qw, ca_qwT, DMODEL, DMODEL);
  addjob(5, ca_kw, ca_kvT, DMODEL, DMODEL);
  addjob(6, ca_vw, ca_kvT + (size_t)DMODEL * DMODEL, DMODEL, DMODEL);
  addjob(7, ca_ow, ca_owT, DMODEL, DMODEL);
  addjob(8, fw1, w1T, DMODEL, FFND);
  addjob(9, fw2, w2T, FFND, DMODEL);
  wconv<<<t, 256, 0, stream>>>(jobs);

  f2b_kernel<<<(LCTX * DMODEL) / 256, 256, 0, stream>>>(ctx, ctxb, LCTX * DMODEL);

  // ---- self attention branch ----
  ln_mod<<<S_LEN, 256, 0, stream>>>(x, modc + DMODEL, modc, 1.f, h_bf);
  dim3 g12(29, 12);
  {
    Segs sg;
    sg.s[0] = { sa_qb, pre0, nullptr };
    sg.s[1] = { sa_kb, x2,   nullptr };
    sg.s[2] = { sa_vb, nullptr, vb   };
    gemm_seg<<<dim3(29, 36), 256, 0, stream>>>(h_bf, sa_qkvT, sg, S_LEN, 3 * DMODEL, DMODEL);
  }
  rms_rope<<<S_LEN, 256, 0, stream>>>(pre0, sa_nq, ropec, ropes, qb);
  rms_rope<<<S_LEN, 256, 0, stream>>>(x2, sa_nk, ropec, ropes, kb);
  vtrans<<<dim3(SPAD_SELF / 32, 12), 256, 0, stream>>>(vb, vts, S_LEN, SPAD_SELF);
  flash_attn<<<dim3(57, 12), 256, 0, stream>>>(qb, kb, vts, ab, S_LEN, S_LEN, SPAD_SELF);
  gemm_bt<2><<<g12, 256, 0, stream>>>(ab, sa_owT, sa_ob, x, modc + 2 * DMODEL, x2, nullptr, S_LEN, DMODEL, DMODEL, DMODEL);

  // ---- cross attention branch ----
  ln_mod<<<S_LEN, 256, 0, stream>>>(x2, n3w, n3b, 0.f, h_bf);
  gemm_bt<1><<<g12, 256, 0, stream>>>(h_bf, ca_qwT, ca_qb, nullptr, nullptr, pre0, nullptr, S_LEN, DMODEL, DMODEL, DMODEL);
  {
    Segs sg;
    sg.s[0] = { ca_kb, pre2, nullptr };
    sg.s[1] = { ca_vb, nullptr, v2b  };
    sg.s[2] = { ca_vb, nullptr, v2b  };
    gemm_seg<<<dim3(4, 24), 256, 0, stream>>>(ctxb, ca_kvT, sg, LCTX, 2 * DMODEL, DMODEL);
  }
  rms_rope<<<S_LEN, 256, 0, stream>>>(pre0, ca_nq, nullptr, nullptr, qb);
  rms_rope<<<LCTX, 256, 0, stream>>>(pre2, ca_nk, nullptr, nullptr, k2b);
  vtrans<<<dim3(16, 12), 256, 0, stream>>>(v2b, vtc, LCTX, LCTX);
  flash_attn<<<dim3(57, 12), 256, 0, stream>>>(qb, k2b, vtc, ab, S_LEN, LCTX, LCTX);
  gemm_bt<2><<<g12, 256, 0, stream>>>(ab, ca_owT, ca_ob, x2, nullptr, pre0, nullptr, S_LEN, DMODEL, DMODEL, DMODEL);

  // ---- FFN ----
  ln_mod<<<S_LEN, 256, 0, stream>>>(pre0, modc + 4 * DMODEL, modc + 3 * DMODEL, 1.f, h_bf);
  gemm_bt<3><<<dim3(29, 70), 256, 0, stream>>>(h_bf, w1T, fb1, nullptr, nullptr, nullptr, fmid, S_LEN, FFND, DMODEL, DMODEL);
  gemm_bt<5><<<dim3(29, 12, 2), 256, 0, stream>>>(fmid, w2T, nullptr, nullptr, nullptr, fpart, nullptr, S_LEN, DMODEL, FFND, FFND / 2);
  ffn2_reduce<<<(S_LEN * DMODEL / 4 + 255) / 256, 256, 0, stream>>>(fpart, pre0, fb2, modc + 5 * DMODEL, out, S_LEN * DMODEL);
}

// Round 5
// 1008.033 us; speedup vs baseline: 1.2700x; 1.0469x over previous
//
#include <hip/hip_runtime.h>
#include <cstdint>

#define S_LEN 3600
#define DMODEL 1536
#define LCTX 512
#define NH 12
#define HDIM 128
#define FFND 8960
#define SPAD_SELF 3648

typedef short v8s __attribute__((ext_vector_type(8)));
typedef float v4f __attribute__((ext_vector_type(4)));
typedef unsigned short u16b;
typedef unsigned int u32b;

#define AS1 __attribute__((address_space(1)))
#define AS3 __attribute__((address_space(3)))

__device__ __forceinline__ void gl_lds16(const void* g, void* l){
  __builtin_amdgcn_global_load_lds((AS1 const void*)g, (AS3 void*)l, 16, 0, 0);
}

__device__ __forceinline__ u16b f2b(float f){
  union { float f; u32b i; } x; x.f = f;
  u32b r = x.i + 0x7fffu + ((x.i >> 16) & 1u);
  return (u16b)(r >> 16);
}

__device__ __forceinline__ u32b cvtpk(float a, float b){
  u32b r;
  asm("v_cvt_pk_bf16_f32 %0, %1, %2" : "=v"(r) : "v"(a), "v"(b));
  return r;
}

__device__ __forceinline__ int swz4(int row){ return (row ^ (row >> 2)) & 3; }

// ---------------- small elementwise kernels ----------------
__global__ void add_vec(const float* __restrict__ a, const float* __restrict__ b,
                        float* __restrict__ o, int n){
  int i = blockIdx.x * 256 + threadIdx.x;
  if (i < n) o[i] = a[i] + b[i];
}

__global__ void f2b_kernel(const float* __restrict__ in, u16b* __restrict__ out, int n){
  int i = blockIdx.x * 256 + threadIdx.x;
  if (i < n) out[i] = f2b(in[i]);
}

// ---------------- fused transpose-convert of all weights ----------------
struct WJob { const float* W; u16b* WT; int K; int N; int t0; };
struct WJobs { WJob j[10]; };

__global__ __launch_bounds__(256) void wconv(WJobs jobs){
  __shared__ float tile[32][33];
  int b = blockIdx.x;
  int ji = 0;
  #pragma unroll
  for (int i = 0; i < 10; ++i) if (b >= jobs.j[i].t0) ji = i;
  WJob jb = jobs.j[ji];
  int rel = b - jb.t0;
  int ntn = jb.N / 32;
  int k0 = (rel / ntn) * 32, n0 = (rel % ntn) * 32;
  int tx = threadIdx.x & 31, ty = threadIdx.x >> 5;
  #pragma unroll
  for (int r = ty; r < 32; r += 8) tile[r][tx] = jb.W[(size_t)(k0 + r) * jb.N + n0 + tx];
  __syncthreads();
  #pragma unroll
  for (int r = ty; r < 32; r += 8) jb.WT[(size_t)(n0 + r) * jb.K + k0 + tx] = f2b(tile[tx][r]);
}

// ---------------- per-head V transpose: V[S][12*128] -> Vt[12][128][Spad] ----------------
__global__ __launch_bounds__(256) void vtrans(const u16b* __restrict__ V,
                                              u16b* __restrict__ Vt,
                                              int S, int Spad){
  __shared__ u16b t[32][136];
  int h = blockIdx.y, kb = blockIdx.x * 32, tid = threadIdx.x;
  int row = tid >> 3, ch = tid & 7;
  int key = kb + row;
  if (key < S){
    float4 a = *(const float4*)(V + (size_t)key * DMODEL + h * HDIM + ch * 16);
    float4 b = *(const float4*)(V + (size_t)key * DMODEL + h * HDIM + ch * 16 + 8);
    *(float4*)&t[row][ch * 16] = a;
    *(float4*)&t[row][ch * 16 + 8] = b;
  } else {
    float4 z = {0.f, 0.f, 0.f, 0.f};
    *(float4*)&t[row][ch * 16] = z;
    *(float4*)&t[row][ch * 16 + 8] = z;
  }
  __syncthreads();
  int hd = tid >> 1, kc = (tid & 1) * 16;
  u16b* dst = Vt + ((size_t)h * HDIM + hd) * Spad + kb + kc;
  #pragma unroll
  for (int e = 0; e < 16; e += 2){
    u32b pk = ((u32b)t[kc + e][hd]) | (((u32b)t[kc + e + 1][hd]) << 16);
    *(u32b*)(dst + e) = pk;
  }
}

// ---------------- LayerNorm (mod or affine) -> bf16 ----------------
__global__ __launch_bounds__(256) void ln_mod(const float* __restrict__ X,
                                              const float* __restrict__ gamma,
                                              const float* __restrict__ beta,
                                              float gadd, u16b* __restrict__ out){
  int row = blockIdx.x;
  const float* xr = X + (size_t)row * DMODEL;
  int tid = threadIdx.x;
  float v[6]; float s1 = 0.f, s2 = 0.f;
  #pragma unroll
  for (int j = 0; j < 6; ++j){ v[j] = xr[tid + j * 256]; s1 += v[j]; s2 += v[j] * v[j]; }
  #pragma unroll
  for (int o = 1; o < 64; o <<= 1){ s1 += __shfl_xor(s1, o); s2 += __shfl_xor(s2, o); }
  __shared__ float red[8];
  int wid = tid >> 6, lane = tid & 63;
  if (!lane){ red[wid * 2] = s1; red[wid * 2 + 1] = s2; }
  __syncthreads();
  s1 = red[0] + red[2] + red[4] + red[6];
  s2 = red[1] + red[3] + red[5] + red[7];
  float mu = s1 / DMODEL;
  float var = s2 / DMODEL - mu * mu;
  float rstd = rsqrtf(var + 1e-6f);
  #pragma unroll
  for (int j = 0; j < 6; ++j){
    int c = tid + j * 256;
    float g = gamma[c] + gadd;
    float b = beta[c];
    out[(size_t)row * DMODEL + c] = f2b((v[j] - mu) * rstd * g + b);
  }
}

// ---------------- RMSNorm (+optional RoPE) fp32 -> bf16, optional output scale ----------------
__global__ __launch_bounds__(256) void rms_rope(const float* __restrict__ X,
                                                const float* __restrict__ w,
                                                const float* __restrict__ cosT,
                                                const float* __restrict__ sinT,
                                                float qmul,
                                                u16b* __restrict__ out){
  int row = blockIdx.x;
  const float* xr = X + (size_t)row * DMODEL;
  int tid = threadIdx.x;
  float2 v[3]; float ss = 0.f;
  #pragma unroll
  for (int j = 0; j < 3; ++j){
    v[j] = *(const float2*)(xr + 2 * (tid + j * 256));
    ss += v[j].x * v[j].x + v[j].y * v[j].y;
  }
  #pragma unroll
  for (int o = 1; o < 64; o <<= 1) ss += __shfl_xor(ss, o);
  __shared__ float red[4];
  int wid = tid >> 6, lane = tid & 63;
  if (!lane) red[wid] = ss;
  __syncthreads();
  ss = red[0] + red[1] + red[2] + red[3];
  float rstd = rsqrtf(ss / DMODEL + 1e-6f);
  #pragma unroll
  for (int j = 0; j < 3; ++j){
    int p = tid + j * 256;
    float xe = v[j].x * rstd * w[2 * p];
    float xo = v[j].y * rstd * w[2 * p + 1];
    float oe, oo;
    if (cosT){
      int d = p & 63;
      float c = cosT[row * 64 + d], sn = sinT[row * 64 + d];
      oe = xe * c - xo * sn; oo = xe * sn + xo * c;
    } else { oe = xe; oo = xo; }
    oe *= qmul; oo *= qmul;
    u32b packed = ((u32b)f2b(oe)) | (((u32b)f2b(oo)) << 16);
    *(u32b*)(out + (size_t)row * DMODEL + 2 * p) = packed;
  }
}

// ---------------- bf16 MFMA GEMM (gload_lds dbuf, 1 barrier/K-step) ----------------
template<int EPI>
__global__ __launch_bounds__(256, 2) void gemm_bt(
    const u16b* __restrict__ A, const u16b* __restrict__ BT,
    const float* __restrict__ bias, const float* __restrict__ res,
    const float* __restrict__ gate, float* __restrict__ outF,
    u16b* __restrict__ outB, int M, int N, int K, int kLen)
{
  __shared__ char Asm[2][8192];
  __shared__ char Bsm[2][8192];
  const int tid = threadIdx.x, lane = tid & 63, wid = tid >> 6;
  const int bm = blockIdx.x * 128, bn = blockIdx.y * 128;
  const int kbase = blockIdx.z * kLen;
  const int wm = (wid >> 1) * 64, wn = (wid & 1) * 64;
  v4f acc[4][4] = {};

  auto stage = [&](int buf, int k0){
    #pragma unroll
    for (int c = 0; c < 2; ++c){
      int seg = wid * 2 + c;
      int l = seg * 64 + lane;
      int row = l >> 2, cs = l & 3;
      int col = cs ^ swz4(row);
      gl_lds16(A + (size_t)min(bm + row, M - 1) * K + kbase + k0 + col * 8,
               Asm[buf] + seg * 1024);
      gl_lds16(BT + (size_t)(bn + row) * K + kbase + k0 + col * 8,
               Bsm[buf] + seg * 1024);
    }
  };

  const int nt = kLen / 32;
  int cur = 0;
  stage(0, 0);
  __syncthreads();
  const int chk = lane >> 4, qr = lane & 15;
  for (int t = 0; t < nt; ++t){
    if (t + 1 < nt) stage(cur ^ 1, (t + 1) * 32);
    char* Ab = Asm[cur]; char* Bb = Bsm[cur];
    v8s af[4], bfr[4];
    #pragma unroll
    for (int f = 0; f < 4; ++f){
      int rowa = wm + f * 16 + qr;
      af[f] = *(const v8s*)(Ab + rowa * 64 + ((chk ^ swz4(rowa)) * 16));
      int rowb = wn + f * 16 + qr;
      bfr[f] = *(const v8s*)(Bb + rowb * 64 + ((chk ^ swz4(rowb)) * 16));
    }
    __builtin_amdgcn_s_setprio(1);
    #pragma unroll
    for (int i = 0; i < 4; ++i)
      #pragma unroll
      for (int j = 0; j < 4; ++j)
        acc[i][j] = __builtin_amdgcn_mfma_f32_16x16x32_bf16(af[i], bfr[j], acc[i][j], 0, 0, 0);
    __builtin_amdgcn_s_setprio(0);
    __syncthreads();
    cur ^= 1;
  }
  const int rr = lane >> 4;
  #pragma unroll
  for (int i = 0; i < 4; ++i){
    #pragma unroll
    for (int j = 0; j < 4; ++j){
      int n = bn + wn + j * 16 + qr;
      float bv = (EPI != 5 && bias) ? bias[n] : 0.f;
      float gv = (EPI == 2 && gate) ? gate[n] : 1.f;
      #pragma unroll
      for (int r = 0; r < 4; ++r){
        int m = bm + wm + i * 16 + rr * 4 + r;
        if (m < M){
          float val = acc[i][j][r] + bv;
          size_t idx = (size_t)m * N + n;
          if (EPI == 0) outB[idx] = f2b(val);
          else if (EPI == 1) outF[idx] = val;
          else if (EPI == 2) outF[idx] = res[idx] + gv * val;
          else if (EPI == 5) outF[(size_t)blockIdx.z * M * N + idx] = val;
          else {
            float t3 = val * val * val;
            float th = tanhf(0.7978845608028654f * (val + 0.044715f * t3));
            outB[idx] = f2b(0.5f * val * (1.f + th));
          }
        }
      }
    }
  }
}

// ---------------- segmented GEMM (fused QKV / KV) ----------------
struct Seg { const float* bias; float* outF; u16b* outB; };
struct Segs { Seg s[3]; };

__global__ __launch_bounds__(256, 2) void gemm_seg(
    const u16b* __restrict__ A, const u16b* __restrict__ BT,
    Segs segs, int M, int N, int K)
{
  __shared__ char Asm[2][8192];
  __shared__ char Bsm[2][8192];
  const int tid = threadIdx.x, lane = tid & 63, wid = tid >> 6;
  const int bm = blockIdx.x * 128, bn = blockIdx.y * 128;
  const int wm = (wid >> 1) * 64, wn = (wid & 1) * 64;
  v4f acc[4][4] = {};

  auto stage = [&](int buf, int k0){
    #pragma unroll
    for (int c = 0; c < 2; ++c){
      int seg = wid * 2 + c;
      int l = seg * 64 + lane;
      int row = l >> 2, cs = l & 3;
      int col = cs ^ swz4(row);
      gl_lds16(A + (size_t)min(bm + row, M - 1) * K + k0 + col * 8,
               Asm[buf] + seg * 1024);
      gl_lds16(BT + (size_t)(bn + row) * K + k0 + col * 8,
               Bsm[buf] + seg * 1024);
    }
  };

  const int nt = K / 32;
  int cur = 0;
  stage(0, 0);
  __syncthreads();
  const int chk = lane >> 4, qr = lane & 15;
  for (int t = 0; t < nt; ++t){
    if (t + 1 < nt) stage(cur ^ 1, (t + 1) * 32);
    char* Ab = Asm[cur]; char* Bb = Bsm[cur];
    v8s af[4], bfr[4];
    #pragma unroll
    for (int f = 0; f < 4; ++f){
      int rowa = wm + f * 16 + qr;
      af[f] = *(const v8s*)(Ab + rowa * 64 + ((chk ^ swz4(rowa)) * 16));
      int rowb = wn + f * 16 + qr;
      bfr[f] = *(const v8s*)(Bb + rowb * 64 + ((chk ^ swz4(rowb)) * 16));
    }
    __builtin_amdgcn_s_setprio(1);
    #pragma unroll
    for (int i = 0; i < 4; ++i)
      #pragma unroll
      for (int j = 0; j < 4; ++j)
        acc[i][j] = __builtin_amdgcn_mfma_f32_16x16x32_bf16(af[i], bfr[j], acc[i][j], 0, 0, 0);
    __builtin_amdgcn_s_setprio(0);
    __syncthreads();
    cur ^= 1;
  }
  const int seg = bn / 1536;
  const Seg sg = segs.s[seg];
  const int rr = lane >> 4;
  #pragma unroll
  for (int i = 0; i < 4; ++i){
    #pragma unroll
    for (int j = 0; j < 4; ++j){
      int nloc = bn - seg * 1536 + wn + j * 16 + qr;
      float bv = sg.bias[nloc];
      #pragma unroll
      for (int r = 0; r < 4; ++r){
        int m = bm + wm + i * 16 + rr * 4 + r;
        if (m < M){
          float val = acc[i][j][r] + bv;
          size_t idx = (size_t)m * 1536 + nloc;
          if (sg.outB) sg.outB[idx] = f2b(val);
          else sg.outF[idx] = val;
        }
      }
    }
  }
}

// ---------------- FFN2 split-K reduce ----------------
__global__ __launch_bounds__(256) void ffn2_reduce(const float* __restrict__ part,
                                                   const float* __restrict__ res,
                                                   const float* __restrict__ bias,
                                                   const float* __restrict__ gate,
                                                   float* __restrict__ out, int total){
  int i4 = blockIdx.x * 256 + threadIdx.x;
  if (i4 * 4 >= total) return;
  int base = i4 * 4;
  int n = base % DMODEL;
  float4 p0 = *(const float4*)(part + base);
  float4 p1 = *(const float4*)(part + (size_t)total + base);
  float4 rs = *(const float4*)(res + base);
  float4 bv = *(const float4*)(bias + n);
  float4 gv = *(const float4*)(gate + n);
  float4 o;
  o.x = rs.x + gv.x * (p0.x + p1.x + bv.x);
  o.y = rs.y + gv.y * (p0.y + p1.y + bv.y);
  o.z = rs.z + gv.z * (p0.z + p1.z + bv.z);
  o.w = rs.w + gv.w * (p0.w + p1.w + bv.w);
  *(float4*)(out + base) = o;
}

// ---------------- split-flash merge: O = (w0*o0 + w1*o1)/(w0*l0 + w1*l1) ----------------
__global__ __launch_bounds__(256) void merge_o(const float* __restrict__ op0,
                                               const float* __restrict__ op1,
                                               const float2* __restrict__ ml,
                                               u16b* __restrict__ outO, int Sq){
  int i4 = blockIdx.x * 256 + threadIdx.x;
  const int perRow = DMODEL / 4;
  if (i4 >= Sq * perRow) return;
  int row = i4 / perRow, c4 = (i4 % perRow) * 4;
  int h = c4 >> 7;
  float2 ml0 = ml[h * Sq + row];
  float2 ml1 = ml[NH * Sq + h * Sq + row];
  float M = fmaxf(ml0.x, ml1.x);
  float w0 = exp2f(ml0.x - M), w1 = exp2f(ml1.x - M);
  float inv = 1.f / (ml0.y * w0 + ml1.y * w1);
  float4 a = *(const float4*)(op0 + (size_t)row * DMODEL + c4);
  float4 b = *(const float4*)(op1 + (size_t)row * DMODEL + c4);
  u32b lo = ((u32b)f2b((a.x * w0 + b.x * w1) * inv)) | (((u32b)f2b((a.y * w0 + b.y * w1) * inv)) << 16);
  u32b hi = ((u32b)f2b((a.z * w0 + b.z * w1) * inv)) | (((u32b)f2b((a.w * w0 + b.w * w1) * inv)) << 16);
  uint2 w2; w2.x = lo; w2.y = hi;
  *(uint2*)(outO + (size_t)row * DMODEL + c4) = w2;
}

// ---------------- flash attention: KVBLK=64, single KV buffer, key-split x2 ----------------
// Q pre-scaled by scale*log2e -> scores in log2 domain. V pre-transposed Vt[h][hd][Spad].
__global__ __launch_bounds__(256, 4) void flash_attn(
    const u16b* __restrict__ Q, const u16b* __restrict__ Kp,
    const u16b* __restrict__ Vt, u16b* __restrict__ O,
    float* __restrict__ op0, float* __restrict__ op1,
    float2* __restrict__ mlbuf,
    int Sq, int Sk, int ksplit, int Spad)
{
  __shared__ char KV[32768];      // K 16KB [key 64][hd granules swz] | V 16KB [hd 128][key granules swz]
  __shared__ char Pall[8192];     // per wave 2KB: [q 16][key 64] swz
  const int tid = threadIdx.x, lane = tid & 63, wid = tid >> 6;
  const int h = blockIdx.y;
  const int z = blockIdx.z;
  const int kbeg = z * ksplit;
  const int kend = min(kbeg + ksplit, Sk);
  const int q0 = blockIdx.x * 64 + wid * 16;
  const int qq = lane & 15, cc = lane >> 4;
  char* Kb = KV; char* Vb = KV + 16384;
  char* Pb = Pall + wid * 2048;

  v8s qf[4];
  {
    int qrow = min(q0 + qq, Sq - 1);
    const u16b* qp = Q + (size_t)qrow * DMODEL + h * HDIM + cc * 8;
    #pragma unroll
    for (int ks = 0; ks < 4; ++ks) qf[ks] = *(const v8s*)(qp + ks * 32);
  }

  auto stage = [&](int kb0){
    #pragma unroll
    for (int c = 0; c < 4; ++c){
      int seg = wid * 4 + c;
      int g = seg * 64 + lane;
      int krow = g >> 4, kcol = (g & 15) ^ (krow & 7);
      gl_lds16(Kp + (size_t)min(kb0 + krow, Sk - 1) * DMODEL + h * HDIM + kcol * 8,
               Kb + seg * 1024);
      int vrow = g >> 3, vcol = (g & 7) ^ (vrow & 7);
      gl_lds16(Vt + ((size_t)h * HDIM + vrow) * Spad + kb0 + vcol * 8,
               Vb + seg * 1024);
    }
  };

  float mrun = -1e30f, lrun = 0.f;
  v4f oacc[8] = {};
  const int nt = (kend - kbeg + 63) >> 6;

  for (int t = 0; t < nt; ++t){
    int kb0 = kbeg + (t << 6);
    stage(kb0);
    __syncthreads();
    // ---- QK^T (log2 domain; Q pre-scaled) ----
    v4f sc[4];
    __builtin_amdgcn_s_setprio(1);
    #pragma unroll
    for (int sub = 0; sub < 4; ++sub){
      v4f sa = {0.f, 0.f, 0.f, 0.f};
      int row = sub * 16 + qq;
      #pragma unroll
      for (int ks = 0; ks < 4; ++ks){
        v8s kf = *(const v8s*)(Kb + row * 256 + (((ks * 4 + cc) ^ (row & 7)) * 16));
        sa = __builtin_amdgcn_mfma_f32_16x16x32_bf16(kf, qf[ks], sa, 0, 0, 0);
      }
      sc[sub] = sa;
    }
    __builtin_amdgcn_s_setprio(0);
    if (kb0 + 64 > kend){
      #pragma unroll
      for (int sub = 0; sub < 4; ++sub)
        #pragma unroll
        for (int r = 0; r < 4; ++r)
          if (kb0 + sub * 16 + cc * 4 + r >= kend) sc[sub][r] = -1e30f;
    }
    // ---- online softmax (log2), defer-max, tree reduces ----
    float m01 = fmaxf(fmaxf(sc[0][0], sc[0][1]), fmaxf(sc[0][2], sc[0][3]));
    float m23 = fmaxf(fmaxf(sc[1][0], sc[1][1]), fmaxf(sc[1][2], sc[1][3]));
    float m45 = fmaxf(fmaxf(sc[2][0], sc[2][1]), fmaxf(sc[2][2], sc[2][3]));
    float m67 = fmaxf(fmaxf(sc[3][0], sc[3][1]), fmaxf(sc[3][2], sc[3][3]));
    float pmax = fmaxf(fmaxf(m01, m23), fmaxf(m45, m67));
    pmax = fmaxf(pmax, __shfl_xor(pmax, 16));
    pmax = fmaxf(pmax, __shfl_xor(pmax, 32));
    if (!__all(pmax <= mrun + 11.54f)){
      float mnew = fmaxf(mrun, pmax);
      float alpha = exp2f(mrun - mnew);
      mrun = mnew;
      float alr[4];
      #pragma unroll
      for (int r = 0; r < 4; ++r) alr[r] = __shfl(alpha, cc * 4 + r);
      #pragma unroll
      for (int f = 0; f < 8; ++f)
        #pragma unroll
        for (int r = 0; r < 4; ++r) oacc[f][r] *= alr[r];
      lrun *= alpha;
    }
    float csum = 0.f;
    #pragma unroll
    for (int sub = 0; sub < 4; ++sub){
      float s0 = 0.f, s1 = 0.f;
      #pragma unroll
      for (int r = 0; r < 4; r += 2){
        float p0 = exp2f(sc[sub][r] - mrun);
        float p1 = exp2f(sc[sub][r + 1] - mrun);
        sc[sub][r] = p0; sc[sub][r + 1] = p1;
        s0 += p0; s1 += p1;
      }
      csum += s0 + s1;
    }
    csum += __shfl_xor(csum, 16);
    csum += __shfl_xor(csum, 32);
    lrun += csum;
    // ---- P -> per-wave LDS tile (cvt_pk) ----
    #pragma unroll
    for (int sub = 0; sub < 4; ++sub){
      uint2 w2;
      w2.x = cvtpk(sc[sub][0], sc[sub][1]);
      w2.y = cvtpk(sc[sub][2], sc[sub][3]);
      int gI = sub * 2 + (cc >> 1);
      *(uint2*)(Pb + qq * 128 + ((gI ^ (qq & 7)) * 16) + (cc & 1) * 8) = w2;
    }
    // ---- PV ----
    v8s pf0 = *(const v8s*)(Pb + qq * 128 + (((cc) ^ (qq & 7)) * 16));
    v8s pf1 = *(const v8s*)(Pb + qq * 128 + (((4 + cc) ^ (qq & 7)) * 16));
    __builtin_amdgcn_s_setprio(1);
    #pragma unroll
    for (int hdb = 0; hdb < 8; ++hdb){
      int row = hdb * 16 + qq;
      v8s vf0 = *(const v8s*)(Vb + row * 128 + (((cc) ^ (row & 7)) * 16));
      v8s vf1 = *(const v8s*)(Vb + row * 128 + (((4 + cc) ^ (row & 7)) * 16));
      oacc[hdb] = __builtin_amdgcn_mfma_f32_16x16x32_bf16(pf0, vf0, oacc[hdb], 0, 0, 0);
      oacc[hdb] = __builtin_amdgcn_mfma_f32_16x16x32_bf16(pf1, vf1, oacc[hdb], 0, 0, 0);
    }
    __builtin_amdgcn_s_setprio(0);
    __syncthreads();
  }

  if (mlbuf){
    float* op = z ? op1 : op0;
    #pragma unroll
    for (int hdb = 0; hdb < 8; ++hdb)
      #pragma unroll
      for (int r = 0; r < 4; ++r){
        int qrow = q0 + cc * 4 + r;
        if (qrow < Sq)
          op[(size_t)qrow * DMODEL + h * HDIM + hdb * 16 + qq] = oacc[hdb][r];
      }
    if (cc == 0 && q0 + qq < Sq)
      mlbuf[(size_t)z * NH * Sq + (size_t)h * Sq + q0 + qq] = make_float2(mrun, lrun);
  } else {
    float linv = 1.f / lrun;
    float lr[4];
    #pragma unroll
    for (int r = 0; r < 4; ++r) lr[r] = __shfl(linv, cc * 4 + r);
    #pragma unroll
    for (int hdb = 0; hdb < 8; ++hdb)
      #pragma unroll
      for (int r = 0; r < 4; ++r){
        int qrow = q0 + cc * 4 + r;
        if (qrow < Sq)
          O[(size_t)qrow * DMODEL + h * HDIM + hdb * 16 + qq] = f2b(oacc[hdb][r] * lr[r]);
      }
  }
}

// ---------------- host launch ----------------
extern "C" void kernel_launch(void* const* d_in, const int* in_sizes, int n_in,
                              void* d_out, int out_size, void* d_ws, size_t ws_size,
                              hipStream_t stream){
  (void)in_sizes; (void)n_in; (void)out_size; (void)ws_size;
  const float* x     = (const float*)d_in[0];
  const float* ctx   = (const float*)d_in[1];
  const float* t_mod = (const float*)d_in[2];
  const float* ropec = (const float*)d_in[3];
  const float* ropes = (const float*)d_in[4];
  const float* modu  = (const float*)d_in[5];
  const float* sa_qw = (const float*)d_in[6];  const float* sa_qb = (const float*)d_in[7];
  const float* sa_kw = (const float*)d_in[8];  const float* sa_kb = (const float*)d_in[9];
  const float* sa_vw = (const float*)d_in[10]; const float* sa_vb = (const float*)d_in[11];
  const float* sa_ow = (const float*)d_in[12]; const float* sa_ob = (const float*)d_in[13];
  const float* sa_nq = (const float*)d_in[14]; const float* sa_nk = (const float*)d_in[15];
  const float* ca_qw = (const float*)d_in[16]; const float* ca_qb = (const float*)d_in[17];
  const float* ca_kw = (const float*)d_in[18]; const float* ca_kb = (const float*)d_in[19];
  const float* ca_vw = (const float*)d_in[20]; const float* ca_vb = (const float*)d_in[21];
  const float* ca_ow = (const float*)d_in[22]; const float* ca_ob = (const float*)d_in[23];
  const float* ca_nq = (const float*)d_in[24]; const float* ca_nk = (const float*)d_in[25];
  const float* n3w   = (const float*)d_in[26]; const float* n3b   = (const float*)d_in[27];
  const float* fw1   = (const float*)d_in[28]; const float* fb1   = (const float*)d_in[29];
  const float* fw2   = (const float*)d_in[30]; const float* fb2   = (const float*)d_in[31];
  float* out = (float*)d_out;

  const float QSCALE = 0.08838834764831845f * 1.4426950408889634f;

  char* wsp = (char*)d_ws;
  size_t off = 0;
  auto alloc = [&](size_t b){ void* p = wsp + off; off += (b + 255) & ~(size_t)255; return p; };
  const size_t WW = (size_t)DMODEL * DMODEL * 2;
  // persistent (alive through FFN):
  float* modc = (float*)alloc(6 * DMODEL * 4);
  u16b* w1T   = (u16b*)alloc((size_t)FFND * DMODEL * 2);
  u16b* w2T   = (u16b*)alloc((size_t)DMODEL * FFND * 2);
  u16b* h_bf  = (u16b*)alloc((size_t)S_LEN * DMODEL * 2);
  float* pre0 = (float*)alloc((size_t)S_LEN * DMODEL * 4);
  // phase region (dead by FFN time) — fmid + split-K partials overlay it:
  size_t region0 = off;
  u16b* sa_qkvT = (u16b*)alloc(3 * WW);
  u16b* sa_owT  = (u16b*)alloc(WW);
  u16b* ca_qwT  = (u16b*)alloc(WW);
  u16b* ca_kvT  = (u16b*)alloc(2 * WW);
  u16b* ca_owT  = (u16b*)alloc(WW);
  float* x2    = (float*)alloc((size_t)S_LEN * DMODEL * 4);
  float* pre2  = (float*)alloc((size_t)LCTX * DMODEL * 4);
  u16b* qb     = (u16b*)alloc((size_t)S_LEN * DMODEL * 2);
  u16b* kb     = (u16b*)alloc((size_t)S_LEN * DMODEL * 2);   // kb..vb contiguous 22.1MB (cross opart z1)
  u16b* vb     = (u16b*)alloc((size_t)S_LEN * DMODEL * 2);   // ml buffer during flash phases
  u16b* ab     = (u16b*)alloc((size_t)S_LEN * DMODEL * 2);
  u16b* ctxb   = (u16b*)alloc((size_t)LCTX * DMODEL * 2);
  u16b* k2b    = (u16b*)alloc((size_t)LCTX * DMODEL * 2);
  u16b* v2b    = (u16b*)alloc((size_t)LCTX * DMODEL * 2);
  u16b* vts    = (u16b*)alloc((size_t)NH * HDIM * SPAD_SELF * 2);
  u16b* vtc    = (u16b*)alloc((size_t)NH * HDIM * LCTX * 2);
  // FFN-phase overlay:
  u16b* fmid = (u16b*)(wsp + region0);
  float* fpart = (float*)(wsp + region0 + (size_t)S_LEN * FFND * 2);

  add_vec<<<36, 256, 0, stream>>>(modu, t_mod, modc, 6 * DMODEL);

  WJobs jobs; int t = 0;
  auto addjob = [&](int i, const float* w_, u16b* wt, int K, int N){
    jobs.j[i].W = w_; jobs.j[i].WT = wt; jobs.j[i].K = K; jobs.j[i].N = N; jobs.j[i].t0 = t;
    t += (K / 32) * (N / 32);
  };
  addjob(0, sa_qw, sa_qkvT, DMODEL, DMODEL);
  addjob(1, sa_kw, sa_qkvT + (size_t)DMODEL * DMODEL, DMODEL, DMODEL);
  addjob(2, sa_vw, sa_qkvT + (size_t)2 * DMODEL * DMODEL, DMODEL, DMODEL);
  addjob(3, sa_ow, sa_owT, DMODEL, DMODEL);
  addjob(4, ca_qw, ca_qwT, DMODEL, DMODEL);
  addjob(5, ca_kw, ca_kvT, DMODEL, DMODEL);
  addjob(6, ca_vw, ca_kvT + (size_t)DMODEL * DMODEL, DMODEL, DMODEL);
  addjob(7, ca_ow, ca_owT, DMODEL, DMODEL);
  addjob(8, fw1, w1T, DMODEL, FFND);
  addjob(9, fw2, w2T, FFND, DMODEL);
  wconv<<<t, 256, 0, stream>>>(jobs);

  f2b_kernel<<<(LCTX * DMODEL) / 256, 256, 0, stream>>>(ctx, ctxb, LCTX * DMODEL);

  // ---- self attention branch ----
  ln_mod<<<S_LEN, 256, 0, stream>>>(x, modc + DMODEL, modc, 1.f, h_bf);
  dim3 g12(29, 12);
  {
    Segs sg;
    sg.s[0] = { sa_qb, pre0, nullptr };
    sg.s[1] = { sa_kb, x2,   nullptr };
    sg.s[2] = { sa_vb, nullptr, vb   };
    gemm_seg<<<dim3(29, 36), 256, 0, stream>>>(h_bf, sa_qkvT, sg, S_LEN, 3 * DMODEL, DMODEL);
  }
  rms_rope<<<S_LEN, 256, 0, stream>>>(pre0, sa_nq, ropec, ropes, QSCALE, qb);
  rms_rope<<<S_LEN, 256, 0, stream>>>(x2, sa_nk, ropec, ropes, 1.f, kb);
  vtrans<<<dim3(SPAD_SELF / 32, 12), 256, 0, stream>>>(vb, vts, S_LEN, SPAD_SELF);
  // key-split x2: opart z0 -> pre0 (dead), z1 -> x2 (dead); ml -> vb (dead)
  flash_attn<<<dim3(57, 12, 2), 256, 0, stream>>>(qb, kb, vts, ab,
      (float*)pre0, (float*)x2, (float2*)vb, S_LEN, S_LEN, 1856, SPAD_SELF);
  merge_o<<<(S_LEN * (DMODEL / 4) + 255) / 256, 256, 0, stream>>>(
      (const float*)pre0, (const float*)x2, (const float2*)vb, ab, S_LEN);
  gemm_bt<2><<<g12, 256, 0, stream>>>(ab, sa_owT, sa_ob, x, modc + 2 * DMODEL, x2, nullptr, S_LEN, DMODEL, DMODEL, DMODEL);

  // ---- cross attention branch ----
  ln_mod<<<S_LEN, 256, 0, stream>>>(x2, n3w, n3b, 0.f, h_bf);
  gemm_bt<1><<<g12, 256, 0, stream>>>(h_bf, ca_qwT, ca_qb, nullptr, nullptr, pre0, nullptr, S_LEN, DMODEL, DMODEL, DMODEL);
  {
    Segs sg;
    sg.s[0] = { ca_kb, pre2, nullptr };
    sg.s[1] = { ca_vb, nullptr, v2b  };
    sg.s[2] = { ca_vb, nullptr, v2b  };
    gemm_seg<<<dim3(4, 24), 256, 0, stream>>>(ctxb, ca_kvT, sg, LCTX, 2 * DMODEL, DMODEL);
  }
  rms_rope<<<S_LEN, 256, 0, stream>>>(pre0, ca_nq, nullptr, nullptr, QSCALE, qb);
  rms_rope<<<LCTX, 256, 0, stream>>>(pre2, ca_nk, nullptr, nullptr, 1.f, k2b);
  vtrans<<<dim3(16, 12), 256, 0, stream>>>(v2b, vtc, LCTX, LCTX);
  // key-split x2: opart z0 -> pre0 (dead), z1 -> kb..vb span (dead); ml -> vb tail? use v2b-safe: ml -> vts (dead)
  flash_attn<<<dim3(57, 12, 2), 256, 0, stream>>>(qb, k2b, vtc, ab,
      (float*)pre0, (float*)kb, (float2*)vts, S_LEN, LCTX, 256, LCTX);
  merge_o<<<(S_LEN * (DMODEL / 4) + 255) / 256, 256, 0, stream>>>(
      (const float*)pre0, (const float*)kb, (const float2*)vts, ab, S_LEN);
  gemm_bt<2><<<g12, 256, 0, stream>>>(ab, ca_owT, ca_ob, x2, nullptr, pre0, nullptr, S_LEN, DMODEL, DMODEL, DMODEL);

  // ---- FFN ----
  ln_mod<<<S_LEN, 256, 0, stream>>>(pre0, modc + 4 * DMODEL, modc + 3 * DMODEL, 1.f, h_bf);
  gemm_bt<3><<<dim3(29, 70), 256, 0, stream>>>(h_bf, w1T, fb1, nullptr, nullptr, nullptr, fmid, S_LEN, FFND, DMODEL, DMODEL);
  gemm_bt<5><<<dim3(29, 12, 2), 256, 0, stream>>>(fmid, w2T, nullptr, nullptr, nullptr, fpart, nullptr, S_LEN, DMODEL, FFND, FFND / 2);
  ffn2_reduce<<<(S_LEN * DMODEL / 4 + 255) / 256, 256, 0, stream>>>(fpart, pre0, fb2, modc + 5 * DMODEL, out, S_LEN * DMODEL);
}